// Round 6
// baseline (1090.812 us; speedup 1.0000x reference)
//
#include <hip/hip_runtime.h>
#include <hip/hip_fp16.h>
#include <math.h>

static constexpr int BLK = 256;   // 4 waves of 64
static constexpr float BN_EPS = 1e-5f;

__device__ __forceinline__ float sigmoid15(float z) {
    return 1.0f / (1.0f + expf(-1.5f * z));
}

__device__ __forceinline__ unsigned pack_ea(float2 v) {
    unsigned hx = __half_as_ushort(__float2half_rn(v.x));
    unsigned hy = __half_as_ushort(__float2half_rn(v.y));
    return hx | (hy << 16);
}
__device__ __forceinline__ float2 unpack_ea(unsigned u) {
    return make_float2(__half2float(__ushort_as_half((unsigned short)(u & 0xffffu))),
                       __half2float(__ushort_as_half((unsigned short)(u >> 16))));
}

// -------- block-level per-channel (sum, sumsq) reduction into double stats --------
// stats layout per BN: stats[j] = sum_j, stats[16+j] = sumsq_j  (32 doubles / BN)
template<int C>
__device__ __forceinline__ void block_stats_reduce(float (&s)[C], float (&ss)[C],
                                                   double* __restrict__ stats)
{
    #pragma unroll
    for (int j = 0; j < C; ++j) {
        #pragma unroll
        for (int o = 32; o > 0; o >>= 1) {
            s[j]  += __shfl_down(s[j],  o, 64);
            ss[j] += __shfl_down(ss[j], o, 64);
        }
    }
    __shared__ float red[2][C][BLK / 64];
    const int wave = threadIdx.x >> 6, lane = threadIdx.x & 63;
    if (lane == 0) {
        #pragma unroll
        for (int j = 0; j < C; ++j) { red[0][j][wave] = s[j]; red[1][j][wave] = ss[j]; }
    }
    __syncthreads();
    if (threadIdx.x < C) {
        const int j = threadIdx.x;
        float a = 0.f, b = 0.f;
        #pragma unroll
        for (int w = 0; w < BLK / 64; ++w) { a += red[0][j][w]; b += red[1][j][w]; }
        atomicAdd(&stats[j],      (double)a);
        atomicAdd(&stats[16 + j], (double)b);
    }
}

// -------- BN coefficient computation: y = sc*m + bb --------
template<int C>
__device__ __forceinline__ void bn_coefs(const double* __restrict__ stats,
                                         const float* __restrict__ g, const float* __restrict__ b,
                                         double invE, float (&sc)[C], float (&bb)[C])
{
    #pragma unroll
    for (int j = 0; j < C; ++j) {
        const double mu  = stats[j] * invE;
        const double var = stats[16 + j] * invE - mu * mu;
        const float inv = rsqrtf((float)(var + (double)BN_EPS));
        const float gg = g[j];
        sc[j] = gg * inv;
        bb[j] = b[j] - (float)mu * gg * inv;
    }
}

// ============================ CSR build (CSR path) ============================

__global__ __launch_bounds__(BLK) void init_kernel(int* __restrict__ deg, double* __restrict__ stats,
                                                   int* __restrict__ rowstart, int n2, int total)
{
    const int i = blockIdx.x * blockDim.x + threadIdx.x;
    if (i < n2) deg[i] = 0;
    if (i < 288) stats[i] = 0.0;
    if (i == 0) rowstart[n2] = total;
}

__global__ __launch_bounds__(BLK) void hist_kernel(const int* __restrict__ edst,
                                                   const int* __restrict__ pdst,
                                                   int* __restrict__ deg, int N, int E)
{
    const int stride = gridDim.x * blockDim.x;
    for (int e = blockIdx.x * blockDim.x + threadIdx.x; e < E; e += stride) {
        atomicAdd(&deg[edst[e]], 1);
        atomicAdd(&deg[N + pdst[e]], 1);
    }
}

__global__ __launch_bounds__(256) void scan1_kernel(const int* __restrict__ deg,
                                                    int* __restrict__ rowstart,
                                                    int* __restrict__ partials, int n2)
{
    __shared__ int lds[256];
    const int tid = threadIdx.x;
    const int base = blockIdx.x * 1024 + tid * 4;
    int v[4]; int loc = 0;
    #pragma unroll
    for (int r = 0; r < 4; ++r) { v[r] = (base + r < n2) ? deg[base + r] : 0; loc += v[r]; }
    lds[tid] = loc; __syncthreads();
    #pragma unroll
    for (int off = 1; off < 256; off <<= 1) {
        int t = (tid >= off) ? lds[tid - off] : 0;
        __syncthreads();
        lds[tid] += t;
        __syncthreads();
    }
    int excl = lds[tid] - loc;
    int run = excl;
    #pragma unroll
    for (int r = 0; r < 4; ++r) {
        if (base + r < n2) rowstart[base + r] = run;
        run += v[r];
    }
    if (tid == 255) partials[blockIdx.x] = lds[255];
}

__global__ __launch_bounds__(256) void scan2_kernel(int* __restrict__ partials, int n)
{
    __shared__ int lds[256];
    const int tid = threadIdx.x;
    const int base = tid * 4;
    int v[4]; int loc = 0;
    #pragma unroll
    for (int r = 0; r < 4; ++r) { v[r] = (base + r < n) ? partials[base + r] : 0; loc += v[r]; }
    lds[tid] = loc; __syncthreads();
    #pragma unroll
    for (int off = 1; off < 256; off <<= 1) {
        int t = (tid >= off) ? lds[tid - off] : 0;
        __syncthreads();
        lds[tid] += t;
        __syncthreads();
    }
    int excl = lds[tid] - loc;
    int run = excl;
    #pragma unroll
    for (int r = 0; r < 4; ++r) {
        if (base + r < n) partials[base + r] = run;
        run += v[r];
    }
}

// scan stage 3: add block bases; copy to cursor (cursor aliases deg; deg dead after scan1)
__global__ __launch_bounds__(BLK) void scan3_kernel(int* __restrict__ rowstart,
                                                    int* __restrict__ cursor,
                                                    const int* __restrict__ partials, int n2)
{
    const int i = blockIdx.x * blockDim.x + threadIdx.x;
    if (i >= n2) return;
    const int v = rowstart[i] + partials[i >> 10];
    rowstart[i] = v;
    cursor[i] = v;
}

// fill: edge set -> csr_e[pos] = {src, fp16x2(ea)} (ONE 8B scattered write);
//       prop set -> csr_psrc[pos-E] = psrc (one 4B scattered write)
__global__ __launch_bounds__(BLK) void fill_kernel(
    const int* __restrict__ esrc, const int* __restrict__ edst,
    const int* __restrict__ psrc, const int* __restrict__ pdst,
    const float* __restrict__ ea,
    int* __restrict__ cursor, uint2* __restrict__ csr_e,
    unsigned int* __restrict__ csr_psrc, int N, int E)
{
    const int stride = gridDim.x * blockDim.x;
    for (int e = blockIdx.x * blockDim.x + threadIdx.x; e < E; e += stride) {
        const int d = edst[e];
        const float2 eav = ((const float2*)ea)[e];
        const int pos = atomicAdd(&cursor[d], 1);
        csr_e[pos] = make_uint2((unsigned)esrc[e], pack_ea(eav));
        const int p = pdst[e];
        const int pos2 = atomicAdd(&cursor[N + p], 1);
        csr_psrc[pos2 - E] = (unsigned)psrc[e];
    }
}

// ============================ CSR-path layer kernels ============================

// Q projection only (P is recomputed on the fly in node kernels)
template<int CIN, int COUT>
__global__ __launch_bounds__(BLK) void projQ_kernel(
    const float* __restrict__ x, const float* __restrict__ agg_in,
    const float* __restrict__ wn, float* __restrict__ Q, int n)
{
    constexpr int PAD = (COUT + 3) & ~3;
    __shared__ float swn[CIN * COUT];
    for (int i = threadIdx.x; i < CIN * COUT; i += blockDim.x) swn[i] = wn[i];
    __syncthreads();
    const int i = blockIdx.x * blockDim.x + threadIdx.x;
    if (i >= n) return;
    float h[CIN];
    h[0] = x[i];
    #pragma unroll
    for (int k = 1; k < CIN; ++k) h[k] = agg_in[(size_t)i * (CIN - 1) + (k - 1)];
    #pragma unroll
    for (int j = 0; j < COUT; ++j) {
        float q = 0.f;
        #pragma unroll
        for (int k = 0; k < CIN; ++k) q = fmaf(h[k], swn[k * COUT + j], q);
        Q[(size_t)i * PAD + j] = q;
    }
}

// pass 1 (4 threads/node): P-row on the fly; accumulate per-channel sum/sumsq
template<int CIN, int COUT, bool HASEA>
__global__ __launch_bounds__(BLK) void node_stats_kernel(
    const int* __restrict__ rowstart,
    const uint2* __restrict__ csr_e, const unsigned int* __restrict__ csr_psrc,
    const float* __restrict__ x, const float* __restrict__ agg_in,
    const float* __restrict__ ws, const float* __restrict__ Q,
    const float* __restrict__ we,
    double* __restrict__ stats, int N, int base, int koff)
{
    constexpr int PAD = (COUT + 3) & ~3;
    __shared__ float sws[CIN * COUT];
    for (int i = threadIdx.x; i < CIN * COUT; i += blockDim.x) sws[i] = ws[i];
    __syncthreads();
    float we0[COUT], we1[COUT];
    if constexpr (HASEA) {
        #pragma unroll
        for (int j = 0; j < COUT; ++j) { we0[j] = we[j]; we1[j] = we[COUT + j]; }
    }
    float s[COUT], ss[COUT];
    #pragma unroll
    for (int j = 0; j < COUT; ++j) { s[j] = 0.f; ss[j] = 0.f; }
    const int t = blockIdx.x * blockDim.x + threadIdx.x;
    const int i = t >> 2, quad = t & 3;
    if (i < N) {
        float h[CIN];
        h[0] = x[i];
        #pragma unroll
        for (int k = 1; k < CIN; ++k) h[k] = agg_in[(size_t)i * (CIN - 1) + (k - 1)];
        float pp[COUT];
        #pragma unroll
        for (int j = 0; j < COUT; ++j) {
            float p = 0.f;
            #pragma unroll
            for (int k = 0; k < CIN; ++k) p = fmaf(h[k], sws[k * COUT + j], p);
            pp[j] = p;
        }
        const int k0 = rowstart[base + i], k1 = rowstart[base + i + 1];
        for (int k = k0 + quad; k < k1; k += 4) {
            unsigned sn;
            float2 eav;
            if constexpr (HASEA) {
                const uint2 ce = csr_e[k];
                sn = ce.x; eav = unpack_ea(ce.y);
            } else {
                sn = csr_psrc[k - koff];
            }
            #pragma unroll
            for (int j = 0; j < COUT; ++j) {
                float m = pp[j] + Q[(size_t)sn * PAD + j];
                if constexpr (HASEA) m = fmaf(eav.x, we0[j], fmaf(eav.y, we1[j], m));
                s[j] += m; ss[j] = fmaf(m, m, ss[j]);
            }
        }
    }
    block_stats_reduce<COUT>(s, ss, stats);
}

// pass 2 (4 threads/node): P-row on the fly; BN+relu; register accumulate; dense write
template<int CIN, int COUT, bool HASEA>
__global__ __launch_bounds__(BLK) void node_agg_kernel(
    const int* __restrict__ rowstart,
    const uint2* __restrict__ csr_e, const unsigned int* __restrict__ csr_psrc,
    const float* __restrict__ x, const float* __restrict__ agg_in,
    const float* __restrict__ ws, const float* __restrict__ Q,
    const float* __restrict__ we,
    const float* __restrict__ g, const float* __restrict__ b,
    const double* __restrict__ stats,
    float* __restrict__ agg_out, int N, int base, int koff, float invE)
{
    constexpr int PAD = (COUT + 3) & ~3;
    __shared__ float sws[CIN * COUT];
    for (int i = threadIdx.x; i < CIN * COUT; i += blockDim.x) sws[i] = ws[i];
    __syncthreads();
    const int t = blockIdx.x * blockDim.x + threadIdx.x;
    const int i = t >> 2, quad = t & 3;
    if (i >= N) return;
    float we0[COUT], we1[COUT];
    if constexpr (HASEA) {
        #pragma unroll
        for (int j = 0; j < COUT; ++j) { we0[j] = we[j]; we1[j] = we[COUT + j]; }
    }
    float sc[COUT], bb[COUT];
    bn_coefs<COUT>(stats, g, b, (double)invE, sc, bb);
    float h[CIN];
    h[0] = x[i];
    #pragma unroll
    for (int k = 1; k < CIN; ++k) h[k] = agg_in[(size_t)i * (CIN - 1) + (k - 1)];
    float pp[COUT], acc[COUT];
    #pragma unroll
    for (int j = 0; j < COUT; ++j) {
        float p = 0.f;
        #pragma unroll
        for (int k = 0; k < CIN; ++k) p = fmaf(h[k], sws[k * COUT + j], p);
        pp[j] = p; acc[j] = 0.f;
    }
    const int k0 = rowstart[base + i], k1 = rowstart[base + i + 1];
    for (int k = k0 + quad; k < k1; k += 4) {
        unsigned sn;
        float2 eav;
        if constexpr (HASEA) {
            const uint2 ce = csr_e[k];
            sn = ce.x; eav = unpack_ea(ce.y);
        } else {
            sn = csr_psrc[k - koff];
        }
        #pragma unroll
        for (int j = 0; j < COUT; ++j) {
            float m = pp[j] + Q[(size_t)sn * PAD + j];
            if constexpr (HASEA) m = fmaf(eav.x, we0[j], fmaf(eav.y, we1[j], m));
            acc[j] += fmaxf(fmaf(sc[j], m, bb[j]), 0.f);
        }
    }
    #pragma unroll
    for (int j = 0; j < COUT; ++j) {
        acc[j] += __shfl_xor(acc[j], 1, 64);
        acc[j] += __shfl_xor(acc[j], 2, 64);
    }
    if (quad == 0) {
        #pragma unroll
        for (int j = 0; j < COUT; ++j) agg_out[(size_t)i * COUT + j] = acc[j];
    }
}

// ============================ fallback (R1, atomic scatter) ============================

__global__ __launch_bounds__(BLK) void zero_stats_kernel(double* __restrict__ stats, int n)
{
    int i = blockIdx.x * blockDim.x + threadIdx.x;
    if (i < n) stats[i] = 0.0;
}

template<int CIN, int COUT>
__global__ __launch_bounds__(BLK) void projPQ_kernel(
    const float* __restrict__ x, const float* __restrict__ agg_in,
    const float* __restrict__ ws, const float* __restrict__ wn,
    float* __restrict__ P, float* __restrict__ Q, float* __restrict__ agg_out, int n)
{
    __shared__ float sws[CIN * COUT], swn[CIN * COUT];
    for (int i = threadIdx.x; i < CIN * COUT; i += blockDim.x) { sws[i] = ws[i]; swn[i] = wn[i]; }
    __syncthreads();
    const int i = blockIdx.x * blockDim.x + threadIdx.x;
    if (i >= n) return;
    float h[CIN];
    h[0] = x[i];
    #pragma unroll
    for (int k = 1; k < CIN; ++k) h[k] = agg_in[(size_t)i * (CIN - 1) + (k - 1)];
    #pragma unroll
    for (int j = 0; j < COUT; ++j) {
        float p = 0.f, q = 0.f;
        #pragma unroll
        for (int k = 0; k < CIN; ++k) {
            p = fmaf(h[k], sws[k * COUT + j], p);
            q = fmaf(h[k], swn[k * COUT + j], q);
        }
        P[(size_t)i * COUT + j] = p;
        Q[(size_t)i * COUT + j] = q;
        agg_out[(size_t)i * COUT + j] = 0.f;
    }
}

template<int COUT, bool HASEA>
__global__ __launch_bounds__(BLK) void edge_stats_kernel(
    const int* __restrict__ esrc, const int* __restrict__ edst,
    const float* __restrict__ P,  const float* __restrict__ Q,
    const float* __restrict__ ea, const float* __restrict__ we,
    double* __restrict__ stats, int E)
{
    float we0[COUT], we1[COUT];
    if constexpr (HASEA) {
        #pragma unroll
        for (int j = 0; j < COUT; ++j) { we0[j] = we[j]; we1[j] = we[COUT + j]; }
    }
    float s[COUT], ss[COUT];
    #pragma unroll
    for (int j = 0; j < COUT; ++j) { s[j] = 0.f; ss[j] = 0.f; }
    const int stride = gridDim.x * blockDim.x;
    for (int e = blockIdx.x * blockDim.x + threadIdx.x; e < E; e += stride) {
        const int d = edst[e], sn = esrc[e];
        float2 eav = make_float2(0.f, 0.f);
        if constexpr (HASEA) eav = ((const float2* __restrict__)ea)[e];
        #pragma unroll
        for (int j = 0; j < COUT; ++j) {
            float m = P[(size_t)d * COUT + j] + Q[(size_t)sn * COUT + j];
            if constexpr (HASEA) m += eav.x * we0[j] + eav.y * we1[j];
            s[j] += m; ss[j] = fmaf(m, m, ss[j]);
        }
    }
    block_stats_reduce<COUT>(s, ss, stats);
}

template<int COUT, bool HASEA>
__global__ __launch_bounds__(BLK) void edge_scatter_kernel(
    const int* __restrict__ esrc, const int* __restrict__ edst,
    const float* __restrict__ P,  const float* __restrict__ Q,
    const float* __restrict__ ea, const float* __restrict__ we,
    const float* __restrict__ g,  const float* __restrict__ b,
    const double* __restrict__ stats,
    float* __restrict__ agg_out, int E)
{
    float we0[COUT], we1[COUT], sc[COUT], bb[COUT];
    #pragma unroll
    for (int j = 0; j < COUT; ++j) {
        if constexpr (HASEA) { we0[j] = we[j]; we1[j] = we[COUT + j]; }
    }
    bn_coefs<COUT>(stats, g, b, 1.0 / (double)E, sc, bb);
    const int stride = gridDim.x * blockDim.x;
    for (int e = blockIdx.x * blockDim.x + threadIdx.x; e < E; e += stride) {
        const int d = edst[e], sn = esrc[e];
        float2 eav = make_float2(0.f, 0.f);
        if constexpr (HASEA) eav = ((const float2* __restrict__)ea)[e];
        #pragma unroll
        for (int j = 0; j < COUT; ++j) {
            float m = P[(size_t)d * COUT + j] + Q[(size_t)sn * COUT + j];
            if constexpr (HASEA) m += eav.x * we0[j] + eav.y * we1[j];
            const float y = fmaxf(fmaf(sc[j], m, bb[j]), 0.f);
            if (y > 0.f) unsafeAtomicAdd(&agg_out[(size_t)d * COUT + j], y);
        }
    }
}

// ============================ node MLP + edge head (shared) ============================

__global__ __launch_bounds__(BLK) void mlp1_kernel(
    const float* __restrict__ x, const float* __restrict__ agg6,
    const float* __restrict__ pw1, const float* __restrict__ pb1,
    float* __restrict__ t1, double* __restrict__ stats, int n)
{
    __shared__ float w[13 * 8];
    __shared__ float bsh[8];
    for (int i = threadIdx.x; i < 13 * 8; i += blockDim.x) w[i] = pw1[i];
    if (threadIdx.x < 8) bsh[threadIdx.x] = pb1[threadIdx.x];
    __syncthreads();
    const int i = blockIdx.x * blockDim.x + threadIdx.x;
    float s[8], ss[8];
    #pragma unroll
    for (int j = 0; j < 8; ++j) { s[j] = 0.f; ss[j] = 0.f; }
    if (i < n) {
        float h[13];
        h[0] = x[i];
        #pragma unroll
        for (int k = 0; k < 12; ++k) h[k + 1] = agg6[(size_t)i * 12 + k];
        #pragma unroll
        for (int j = 0; j < 8; ++j) {
            float t = bsh[j];
            #pragma unroll
            for (int k = 0; k < 13; ++k) t = fmaf(h[k], w[k * 8 + j], t);
            t = fmaxf(t, 0.f);
            t1[(size_t)i * 8 + j] = t;
            s[j] = t; ss[j] = t * t;
        }
    }
    block_stats_reduce<8>(s, ss, stats);
}

__global__ __launch_bounds__(BLK) void mlp2_kernel(
    const float* __restrict__ t1,
    const float* __restrict__ p1g, const float* __restrict__ p1b,
    const float* __restrict__ pw2, const float* __restrict__ pb2,
    const double* __restrict__ stats1,
    float* __restrict__ t2, double* __restrict__ stats2, int n)
{
    float sc[8], bb[8];
    bn_coefs<8>(stats1, p1g, p1b, 1.0 / (double)n, sc, bb);
    const int i = blockIdx.x * blockDim.x + threadIdx.x;
    float s[4], ss[4];
    #pragma unroll
    for (int j = 0; j < 4; ++j) { s[j] = 0.f; ss[j] = 0.f; }
    if (i < n) {
        float u[8];
        #pragma unroll
        for (int j = 0; j < 8; ++j) u[j] = fmaf(sc[j], t1[(size_t)i * 8 + j], bb[j]);
        #pragma unroll
        for (int j2 = 0; j2 < 4; ++j2) {
            float t = pb2[j2];
            #pragma unroll
            for (int j = 0; j < 8; ++j) t = fmaf(u[j], pw2[j * 4 + j2], t);
            t = fmaxf(t, 0.f);
            t2[(size_t)i * 4 + j2] = t;
            s[j2] = t; ss[j2] = t * t;
        }
    }
    block_stats_reduce<4>(s, ss, stats2);
}

__global__ __launch_bounds__(BLK) void mlp3_kernel(
    const float* __restrict__ t2,
    const float* __restrict__ p2g, const float* __restrict__ p2b,
    const float* __restrict__ pw3, const float* __restrict__ pb3,
    const float* __restrict__ x, const float* __restrict__ agg6,
    const float* __restrict__ ew1, const float* __restrict__ eb1,
    const double* __restrict__ stats2,
    float* __restrict__ power_out, float* __restrict__ A, float* __restrict__ B,
    int n, int astride)
{
    __shared__ float w1[28 * 14];
    for (int i = threadIdx.x; i < 28 * 14; i += blockDim.x) w1[i] = ew1[i];
    __syncthreads();
    float sc[4], bb[4];
    bn_coefs<4>(stats2, p2g, p2b, 1.0 / (double)n, sc, bb);
    const int i = blockIdx.x * blockDim.x + threadIdx.x;
    if (i >= n) return;
    float z = pb3[0];
    #pragma unroll
    for (int j = 0; j < 4; ++j) z = fmaf(fmaf(sc[j], t2[(size_t)i * 4 + j], bb[j]), pw3[j], z);
    const float pw = sigmoid15(z);
    power_out[i] = pw;
    float h[14];
    h[0] = x[i];
    #pragma unroll
    for (int k = 0; k < 12; ++k) h[k + 1] = agg6[(size_t)i * 12 + k];
    h[13] = pw;
    #pragma unroll
    for (int c = 0; c < 14; ++c) {
        float a = eb1[c], b2 = 0.f;
        #pragma unroll
        for (int k = 0; k < 14; ++k) {
            a  = fmaf(h[k], w1[k * 14 + c], a);
            b2 = fmaf(h[k], w1[(14 + k) * 14 + c], b2);
        }
        A[(size_t)i * astride + c] = a;
        B[(size_t)i * astride + c] = b2;
    }
}

__global__ __launch_bounds__(BLK) void ehead_stats_kernel(
    const int* __restrict__ dsrc, const int* __restrict__ ddst,
    const float* __restrict__ A, const float* __restrict__ B,
    double* __restrict__ stats, int E, int astride)
{
    float s[14], ss[14];
    #pragma unroll
    for (int j = 0; j < 14; ++j) { s[j] = 0.f; ss[j] = 0.f; }
    const int stride = gridDim.x * blockDim.x;
    for (int e = blockIdx.x * blockDim.x + threadIdx.x; e < E; e += stride) {
        const int dd = ddst[e], ds = dsrc[e];
        #pragma unroll
        for (int c = 0; c < 14; ++c) {
            const float r = fmaxf(A[(size_t)dd * astride + c] + B[(size_t)ds * astride + c], 0.f);
            s[c] += r; ss[c] = fmaf(r, r, ss[c]);
        }
    }
    block_stats_reduce<14>(s, ss, stats);
}

__global__ __launch_bounds__(BLK) void ehead_final_kernel(
    const int* __restrict__ dsrc, const int* __restrict__ ddst,
    const float* __restrict__ A, const float* __restrict__ B,
    const float* __restrict__ e1g, const float* __restrict__ e1b,
    const float* __restrict__ ew2, const float* __restrict__ eb2,
    const double* __restrict__ stats, float* __restrict__ dir_out, int E, int astride)
{
    float sc[14];
    float off = eb2[0];
    const double invE = 1.0 / (double)E;
    #pragma unroll
    for (int c = 0; c < 14; ++c) {
        const double mu  = stats[c] * invE;
        const double var = stats[16 + c] * invE - mu * mu;
        const float inv = rsqrtf((float)(var + (double)BN_EPS));
        const float gi = e1g[c] * inv;
        sc[c] = gi * ew2[c];
        off += (e1b[c] - (float)mu * gi) * ew2[c];
    }
    const int stride = gridDim.x * blockDim.x;
    for (int e = blockIdx.x * blockDim.x + threadIdx.x; e < E; e += stride) {
        const int dd = ddst[e], ds = dsrc[e];
        float z = off;
        #pragma unroll
        for (int c = 0; c < 14; ++c) {
            const float r = fmaxf(A[(size_t)dd * astride + c] + B[(size_t)ds * astride + c], 0.f);
            z = fmaf(r, sc[c], z);
        }
        dir_out[e] = sigmoid15(z);
    }
}

// ============================ launch ============================

extern "C" void kernel_launch(void* const* d_in, const int* in_sizes, int n_in,
                              void* d_out, int out_size, void* d_ws, size_t ws_size,
                              hipStream_t stream)
{
    const float* x    = (const float*)d_in[0];
    const float* ea   = (const float*)d_in[1];
    const int*   eidx = (const int*)d_in[2];
    const int*   didx = (const int*)d_in[3];
    const int*   pidx = (const int*)d_in[4];
    const float *c1_ws=(const float*)d_in[5],  *c1_wn=(const float*)d_in[6],  *c1_we=(const float*)d_in[7],  *c1_g=(const float*)d_in[8],  *c1_b=(const float*)d_in[9];
    const float *d1_ws=(const float*)d_in[10], *d1_wn=(const float*)d_in[11], *d1_g=(const float*)d_in[12], *d1_b=(const float*)d_in[13];
    const float *c2_ws=(const float*)d_in[14], *c2_wn=(const float*)d_in[15], *c2_we=(const float*)d_in[16], *c2_g=(const float*)d_in[17], *c2_b=(const float*)d_in[18];
    const float *d2_ws=(const float*)d_in[19], *d2_wn=(const float*)d_in[20], *d2_g=(const float*)d_in[21], *d2_b=(const float*)d_in[22];
    const float *c3_ws=(const float*)d_in[23], *c3_wn=(const float*)d_in[24], *c3_we=(const float*)d_in[25], *c3_g=(const float*)d_in[26], *c3_b=(const float*)d_in[27];
    const float *d3_ws=(const float*)d_in[28], *d3_wn=(const float*)d_in[29], *d3_g=(const float*)d_in[30], *d3_b=(const float*)d_in[31];
    const float *pw1=(const float*)d_in[32], *pb1=(const float*)d_in[33], *p1_g=(const float*)d_in[34], *p1_b=(const float*)d_in[35];
    const float *pw2=(const float*)d_in[36], *pb2=(const float*)d_in[37], *p2_g=(const float*)d_in[38], *p2_b=(const float*)d_in[39];
    const float *pw3=(const float*)d_in[40], *pb3=(const float*)d_in[41];
    const float *ew1=(const float*)d_in[42], *eb1=(const float*)d_in[43], *e1_g=(const float*)d_in[44], *e1_b=(const float*)d_in[45];
    const float *ew2=(const float*)d_in[46], *eb2=(const float*)d_in[47];

    const int N = in_sizes[0];
    const int E = in_sizes[2] / 2;
    const int n2 = 2 * N;
    const int *esrc = eidx,     *edst = eidx + E;
    const int *dsrc = didx,     *ddst = didx + E;
    const int *psrc = pidx,     *pdst = pidx + E;

    float* power_out = (float*)d_out;
    float* dir_out   = power_out + N;

    const int gN  = (N + BLK - 1) / BLK;
    const int g2  = (n2 + BLK - 1) / BLK;
    const int g4  = ((size_t)4 * N + BLK - 1) / BLK;   // 4 threads/node
    const int gE  = 1024;                              // reduction kernels (atomic contention cap)
    const int gEf = (E + BLK - 1) / BLK;               // full-size streaming grids
    const float invE = 1.0f / (float)E;

    // ---- CSR-path workspace need (~35.3 MB) ----
    const size_t abFloats = (size_t)32 * N;            // A/B tables reuse csr_e region
    const size_t csreBytes = ((size_t)8 * E > 4 * abFloats) ? (size_t)8 * E : 4 * abFloats;
    const size_t need_csr = 4096
        + sizeof(float) * ((size_t)N * 12   /* Q    */
                         + (size_t)N * 12   /* aggA */
                         + (size_t)N * 12)  /* aggB */
        + csreBytes                         /* csr_e (uint2) / A,B */
        + sizeof(unsigned int) * (size_t)E  /* csr_psrc */
        + sizeof(int) * ((size_t)n2 + 2)    /* rowstart */
        + sizeof(int) * (size_t)n2          /* cursor(=deg) */
        + sizeof(int) * 1024;               /* partials */

    double* stats = (double*)d_ws;                     // 288 doubles

    if (ws_size >= need_csr) {
        // ================= CSR gather path =================
        float* fws  = (float*)((char*)d_ws + 4096);
        float* Q    = fws;                fws += (size_t)N * 12;
        float* aggA = fws;                fws += (size_t)N * 12;
        float* aggB = fws;                fws += (size_t)N * 12;
        uint2* csr_e = (uint2*)fws;
        unsigned int* csr_psrc = (unsigned int*)((char*)csr_e + csreBytes);
        int* rowstart = (int*)(csr_psrc + E);
        int* cursor   = rowstart + (n2 + 2);           // aliases deg
        int* deg      = cursor;
        int* partials = cursor + n2;
        float* t1   = aggA;                             // aggA free after conv stack
        float* t2   = aggA + (size_t)N * 8;
        float* Abuf = (float*)csr_e;                    // csr_e dead after conv stack
        float* Bbuf = Abuf + (size_t)N * 16;

        const int nparts = (n2 + 1023) / 1024;

        init_kernel<<<g2, BLK, 0, stream>>>(deg, stats, rowstart, n2, 2 * E);
        hist_kernel<<<gEf, BLK, 0, stream>>>(edst, pdst, deg, N, E);
        scan1_kernel<<<nparts, 256, 0, stream>>>(deg, rowstart, partials, n2);
        scan2_kernel<<<1, 256, 0, stream>>>(partials, nparts);
        scan3_kernel<<<g2, BLK, 0, stream>>>(rowstart, cursor, partials, n2);
        fill_kernel<<<gEf, BLK, 0, stream>>>(esrc, edst, psrc, pdst, ea, cursor, csr_e, csr_psrc, N, E);

        // L0: c1 (1->2, EA)
        projQ_kernel<1, 2><<<gN, BLK, 0, stream>>>(x, nullptr, c1_wn, Q, N);
        node_stats_kernel<1, 2, true><<<g4, BLK, 0, stream>>>(rowstart, csr_e, csr_psrc, x, nullptr, c1_ws, Q, c1_we, stats + 0, N, 0, 0);
        node_agg_kernel<1, 2, true><<<g4, BLK, 0, stream>>>(rowstart, csr_e, csr_psrc, x, nullptr, c1_ws, Q, c1_we, c1_g, c1_b, stats + 0, aggA, N, 0, 0, invE);
        // L1: d1 (3->4, prop)
        projQ_kernel<3, 4><<<gN, BLK, 0, stream>>>(x, aggA, d1_wn, Q, N);
        node_stats_kernel<3, 4, false><<<g4, BLK, 0, stream>>>(rowstart, csr_e, csr_psrc, x, aggA, d1_ws, Q, nullptr, stats + 32, N, N, E);
        node_agg_kernel<3, 4, false><<<g4, BLK, 0, stream>>>(rowstart, csr_e, csr_psrc, x, aggA, d1_ws, Q, nullptr, d1_g, d1_b, stats + 32, aggB, N, N, E, invE);
        // L2: c2 (5->6, EA)
        projQ_kernel<5, 6><<<gN, BLK, 0, stream>>>(x, aggB, c2_wn, Q, N);
        node_stats_kernel<5, 6, true><<<g4, BLK, 0, stream>>>(rowstart, csr_e, csr_psrc, x, aggB, c2_ws, Q, c2_we, stats + 64, N, 0, 0);
        node_agg_kernel<5, 6, true><<<g4, BLK, 0, stream>>>(rowstart, csr_e, csr_psrc, x, aggB, c2_ws, Q, c2_we, c2_g, c2_b, stats + 64, aggA, N, 0, 0, invE);
        // L3: d2 (7->8, prop)
        projQ_kernel<7, 8><<<gN, BLK, 0, stream>>>(x, aggA, d2_wn, Q, N);
        node_stats_kernel<7, 8, false><<<g4, BLK, 0, stream>>>(rowstart, csr_e, csr_psrc, x, aggA, d2_ws, Q, nullptr, stats + 96, N, N, E);
        node_agg_kernel<7, 8, false><<<g4, BLK, 0, stream>>>(rowstart, csr_e, csr_psrc, x, aggA, d2_ws, Q, nullptr, d2_g, d2_b, stats + 96, aggB, N, N, E, invE);
        // L4: c3 (9->10, EA)
        projQ_kernel<9, 10><<<gN, BLK, 0, stream>>>(x, aggB, c3_wn, Q, N);
        node_stats_kernel<9, 10, true><<<g4, BLK, 0, stream>>>(rowstart, csr_e, csr_psrc, x, aggB, c3_ws, Q, c3_we, stats + 128, N, 0, 0);
        node_agg_kernel<9, 10, true><<<g4, BLK, 0, stream>>>(rowstart, csr_e, csr_psrc, x, aggB, c3_ws, Q, c3_we, c3_g, c3_b, stats + 128, aggA, N, 0, 0, invE);
        // L5: d3 (11->12, prop)
        projQ_kernel<11, 12><<<gN, BLK, 0, stream>>>(x, aggA, d3_wn, Q, N);
        node_stats_kernel<11, 12, false><<<g4, BLK, 0, stream>>>(rowstart, csr_e, csr_psrc, x, aggA, d3_ws, Q, nullptr, stats + 160, N, N, E);
        node_agg_kernel<11, 12, false><<<g4, BLK, 0, stream>>>(rowstart, csr_e, csr_psrc, x, aggA, d3_ws, Q, nullptr, d3_g, d3_b, stats + 160, aggB, N, N, E, invE);

        mlp1_kernel<<<gN, BLK, 0, stream>>>(x, aggB, pw1, pb1, t1, stats + 192, N);
        mlp2_kernel<<<gN, BLK, 0, stream>>>(t1, p1_g, p1_b, pw2, pb2, stats + 192, t2, stats + 224, N);
        mlp3_kernel<<<gN, BLK, 0, stream>>>(t2, p2_g, p2_b, pw3, pb3, x, aggB, ew1, eb1, stats + 224,
                                            power_out, Abuf, Bbuf, N, 16);
        ehead_stats_kernel<<<gE, BLK, 0, stream>>>(dsrc, ddst, Abuf, Bbuf, stats + 256, E, 16);
        ehead_final_kernel<<<gEf, BLK, 0, stream>>>(dsrc, ddst, Abuf, Bbuf, e1_g, e1_b, ew2, eb2,
                                                    stats + 256, dir_out, E, 16);
    } else {
        // ================= fallback: R1 atomic-scatter path (20.8 MB, proven) =================
        float* fws  = (float*)((char*)d_ws + 4096);
        float* P    = fws;                fws += (size_t)N * 14;
        float* Q    = fws;                fws += (size_t)N * 14;
        float* aggA = fws;                fws += (size_t)N * 12;
        float* aggB = fws;                fws += (size_t)N * 12;
        float* t1   = aggA;
        float* t2   = aggA + (size_t)N * 8;
        float* Abuf = P;                  // stride 14
        float* Bbuf = Q;

        zero_stats_kernel<<<2, BLK, 0, stream>>>(stats, 288);

        projPQ_kernel<1, 2><<<gN, BLK, 0, stream>>>(x, nullptr, c1_ws, c1_wn, P, Q, aggA, N);
        edge_stats_kernel<2, true><<<gE, BLK, 0, stream>>>(esrc, edst, P, Q, ea, c1_we, stats + 0, E);
        edge_scatter_kernel<2, true><<<gE, BLK, 0, stream>>>(esrc, edst, P, Q, ea, c1_we, c1_g, c1_b, stats + 0, aggA, E);

        projPQ_kernel<3, 4><<<gN, BLK, 0, stream>>>(x, aggA, d1_ws, d1_wn, P, Q, aggB, N);
        edge_stats_kernel<4, false><<<gE, BLK, 0, stream>>>(psrc, pdst, P, Q, nullptr, nullptr, stats + 32, E);
        edge_scatter_kernel<4, false><<<gE, BLK, 0, stream>>>(psrc, pdst, P, Q, nullptr, nullptr, d1_g, d1_b, stats + 32, aggB, E);

        projPQ_kernel<5, 6><<<gN, BLK, 0, stream>>>(x, aggB, c2_ws, c2_wn, P, Q, aggA, N);
        edge_stats_kernel<6, true><<<gE, BLK, 0, stream>>>(esrc, edst, P, Q, ea, c2_we, stats + 64, E);
        edge_scatter_kernel<6, true><<<gE, BLK, 0, stream>>>(esrc, edst, P, Q, ea, c2_we, c2_g, c2_b, stats + 64, aggA, E);

        projPQ_kernel<7, 8><<<gN, BLK, 0, stream>>>(x, aggA, d2_ws, d2_wn, P, Q, aggB, N);
        edge_stats_kernel<8, false><<<gE, BLK, 0, stream>>>(psrc, pdst, P, Q, nullptr, nullptr, stats + 96, E);
        edge_scatter_kernel<8, false><<<gE, BLK, 0, stream>>>(psrc, pdst, P, Q, nullptr, nullptr, d2_g, d2_b, stats + 96, aggB, E);

        projPQ_kernel<9, 10><<<gN, BLK, 0, stream>>>(x, aggB, c3_ws, c3_wn, P, Q, aggA, N);
        edge_stats_kernel<10, true><<<gE, BLK, 0, stream>>>(esrc, edst, P, Q, ea, c3_we, stats + 128, E);
        edge_scatter_kernel<10, true><<<gE, BLK, 0, stream>>>(esrc, edst, P, Q, ea, c3_we, c3_g, c3_b, stats + 128, aggA, E);

        projPQ_kernel<11, 12><<<gN, BLK, 0, stream>>>(x, aggA, d3_ws, d3_wn, P, Q, aggB, N);
        edge_stats_kernel<12, false><<<gE, BLK, 0, stream>>>(psrc, pdst, P, Q, nullptr, nullptr, stats + 160, E);
        edge_scatter_kernel<12, false><<<gE, BLK, 0, stream>>>(psrc, pdst, P, Q, nullptr, nullptr, d3_g, d3_b, stats + 160, aggB, E);

        mlp1_kernel<<<gN, BLK, 0, stream>>>(x, aggB, pw1, pb1, t1, stats + 192, N);
        mlp2_kernel<<<gN, BLK, 0, stream>>>(t1, p1_g, p1_b, pw2, pb2, stats + 192, t2, stats + 224, N);
        mlp3_kernel<<<gN, BLK, 0, stream>>>(t2, p2_g, p2_b, pw3, pb3, x, aggB, ew1, eb1, stats + 224,
                                            power_out, Abuf, Bbuf, N, 14);
        ehead_stats_kernel<<<gE, BLK, 0, stream>>>(dsrc, ddst, Abuf, Bbuf, stats + 256, E, 14);
        ehead_final_kernel<<<gE, BLK, 0, stream>>>(dsrc, ddst, Abuf, Bbuf, e1_g, e1_b, ew2, eb2,
                                                   stats + 256, dir_out, E, 14);
    }
}

// Round 7
// 952.131 us; speedup vs baseline: 1.1457x; 1.1457x over previous
//
#include <hip/hip_runtime.h>
#include <hip/hip_fp16.h>
#include <math.h>

static constexpr int BLK = 256;   // 4 waves of 64
static constexpr float BN_EPS = 1e-5f;

__device__ __forceinline__ float sigmoid15(float z) {
    return 1.0f / (1.0f + expf(-1.5f * z));
}

__device__ __forceinline__ unsigned pack_ea(float2 v) {
    unsigned hx = __half_as_ushort(__float2half_rn(v.x));
    unsigned hy = __half_as_ushort(__float2half_rn(v.y));
    return hx | (hy << 16);
}
__device__ __forceinline__ float2 unpack_ea(unsigned u) {
    return make_float2(__half2float(__ushort_as_half((unsigned short)(u & 0xffffu))),
                       __half2float(__ushort_as_half((unsigned short)(u >> 16))));
}

// -------- block-level per-channel (sum, sumsq) reduction into double stats --------
template<int C>
__device__ __forceinline__ void block_stats_reduce(float (&s)[C], float (&ss)[C],
                                                   double* __restrict__ stats)
{
    #pragma unroll
    for (int j = 0; j < C; ++j) {
        #pragma unroll
        for (int o = 32; o > 0; o >>= 1) {
            s[j]  += __shfl_down(s[j],  o, 64);
            ss[j] += __shfl_down(ss[j], o, 64);
        }
    }
    __shared__ float red[2][C][BLK / 64];
    const int wave = threadIdx.x >> 6, lane = threadIdx.x & 63;
    if (lane == 0) {
        #pragma unroll
        for (int j = 0; j < C; ++j) { red[0][j][wave] = s[j]; red[1][j][wave] = ss[j]; }
    }
    __syncthreads();
    if (threadIdx.x < C) {
        const int j = threadIdx.x;
        float a = 0.f, b = 0.f;
        #pragma unroll
        for (int w = 0; w < BLK / 64; ++w) { a += red[0][j][w]; b += red[1][j][w]; }
        atomicAdd(&stats[j],      (double)a);
        atomicAdd(&stats[16 + j], (double)b);
    }
}

template<int C>
__device__ __forceinline__ void bn_coefs(const double* __restrict__ stats,
                                         const float* __restrict__ g, const float* __restrict__ b,
                                         double invE, float (&sc)[C], float (&bb)[C])
{
    #pragma unroll
    for (int j = 0; j < C; ++j) {
        const double mu  = stats[j] * invE;
        const double var = stats[16 + j] * invE - mu * mu;
        const float inv = rsqrtf((float)(var + (double)BN_EPS));
        const float gg = g[j];
        sc[j] = gg * inv;
        bb[j] = b[j] - (float)mu * gg * inv;
    }
}

// ============================ CSR build (CSR path) ============================

__global__ __launch_bounds__(BLK) void init_kernel(int* __restrict__ deg, double* __restrict__ stats,
                                                   int* __restrict__ rowstart, int n2, int total)
{
    const int i = blockIdx.x * blockDim.x + threadIdx.x;
    if (i < n2) deg[i] = 0;
    if (i < 288) stats[i] = 0.0;
    if (i == 0) rowstart[n2] = total;
}

// XCD-range-partitioned histogram: groups 0-3 own edge-dst ranges, 4-7 own prop-dst ranges
__global__ __launch_bounds__(BLK) void hist_kernel(const int* __restrict__ edst,
                                                   const int* __restrict__ pdst,
                                                   int* __restrict__ deg, int N, int E)
{
    const int grp = blockIdx.x & 7;
    const int bg  = blockIdx.x >> 3;
    const int gstride = (gridDim.x >> 3) * blockDim.x;
    if (grp < 4) {
        const int lo = (int)((size_t)N * grp / 4), hi = (int)((size_t)N * (grp + 1) / 4);
        for (int e = bg * blockDim.x + threadIdx.x; e < E; e += gstride) {
            const int d = edst[e];
            if (d >= lo && d < hi) atomicAdd(&deg[d], 1);
        }
    } else {
        const int gg = grp - 4;
        const int lo = (int)((size_t)N * gg / 4), hi = (int)((size_t)N * (gg + 1) / 4);
        for (int e = bg * blockDim.x + threadIdx.x; e < E; e += gstride) {
            const int p = pdst[e];
            if (p >= lo && p < hi) atomicAdd(&deg[N + p], 1);
        }
    }
}

__global__ __launch_bounds__(256) void scan1_kernel(const int* __restrict__ deg,
                                                    int* __restrict__ rowstart,
                                                    int* __restrict__ partials, int n2)
{
    __shared__ int lds[256];
    const int tid = threadIdx.x;
    const int base = blockIdx.x * 1024 + tid * 4;
    int v[4]; int loc = 0;
    #pragma unroll
    for (int r = 0; r < 4; ++r) { v[r] = (base + r < n2) ? deg[base + r] : 0; loc += v[r]; }
    lds[tid] = loc; __syncthreads();
    #pragma unroll
    for (int off = 1; off < 256; off <<= 1) {
        int t = (tid >= off) ? lds[tid - off] : 0;
        __syncthreads();
        lds[tid] += t;
        __syncthreads();
    }
    int excl = lds[tid] - loc;
    int run = excl;
    #pragma unroll
    for (int r = 0; r < 4; ++r) {
        if (base + r < n2) rowstart[base + r] = run;
        run += v[r];
    }
    if (tid == 255) partials[blockIdx.x] = lds[255];
}

__global__ __launch_bounds__(256) void scan2_kernel(int* __restrict__ partials, int n)
{
    __shared__ int lds[256];
    const int tid = threadIdx.x;
    const int base = tid * 4;
    int v[4]; int loc = 0;
    #pragma unroll
    for (int r = 0; r < 4; ++r) { v[r] = (base + r < n) ? partials[base + r] : 0; loc += v[r]; }
    lds[tid] = loc; __syncthreads();
    #pragma unroll
    for (int off = 1; off < 256; off <<= 1) {
        int t = (tid >= off) ? lds[tid - off] : 0;
        __syncthreads();
        lds[tid] += t;
        __syncthreads();
    }
    int excl = lds[tid] - loc;
    int run = excl;
    #pragma unroll
    for (int r = 0; r < 4; ++r) {
        if (base + r < n) partials[base + r] = run;
        run += v[r];
    }
}

__global__ __launch_bounds__(BLK) void scan3_kernel(int* __restrict__ rowstart,
                                                    int* __restrict__ cursor,
                                                    const int* __restrict__ partials, int n2)
{
    const int i = blockIdx.x * blockDim.x + threadIdx.x;
    if (i >= n2) return;
    const int v = rowstart[i] + partials[i >> 10];
    rowstart[i] = v;
    cursor[i] = v;
}

// XCD-range-partitioned fill: group g only scatters into its dst range so
// cursor/csr lines stay in one L2 and fill completely before writeback.
__global__ __launch_bounds__(BLK) void fill_kernel(
    const int* __restrict__ esrc, const int* __restrict__ edst,
    const int* __restrict__ psrc, const int* __restrict__ pdst,
    const float* __restrict__ ea,
    int* __restrict__ cursor, uint2* __restrict__ csr_e,
    unsigned int* __restrict__ csr_psrc, int N, int E)
{
    const int grp = blockIdx.x & 7;
    const int bg  = blockIdx.x >> 3;
    const int gstride = (gridDim.x >> 3) * blockDim.x;
    if (grp < 4) {
        const int lo = (int)((size_t)N * grp / 4), hi = (int)((size_t)N * (grp + 1) / 4);
        for (int e = bg * blockDim.x + threadIdx.x; e < E; e += gstride) {
            const int d = edst[e];
            if (d >= lo && d < hi) {
                const float2 eav = ((const float2*)ea)[e];
                const int pos = atomicAdd(&cursor[d], 1);
                csr_e[pos] = make_uint2((unsigned)esrc[e], pack_ea(eav));
            }
        }
    } else {
        const int gg = grp - 4;
        const int lo = (int)((size_t)N * gg / 4), hi = (int)((size_t)N * (gg + 1) / 4);
        for (int e = bg * blockDim.x + threadIdx.x; e < E; e += gstride) {
            const int p = pdst[e];
            if (p >= lo && p < hi) {
                const int pos2 = atomicAdd(&cursor[N + p], 1);
                csr_psrc[pos2 - E] = (unsigned)psrc[e];
            }
        }
    }
}

// ============================ CSR-path layer kernels ============================

// Q projection (only needed standalone for L0)
template<int CIN, int COUT>
__global__ __launch_bounds__(BLK) void projQ_kernel(
    const float* __restrict__ x, const float* __restrict__ agg_in,
    const float* __restrict__ wn, float* __restrict__ Q, int n)
{
    constexpr int PAD = (COUT + 3) & ~3;
    __shared__ float swn[CIN * COUT];
    for (int i = threadIdx.x; i < CIN * COUT; i += blockDim.x) swn[i] = wn[i];
    __syncthreads();
    const int i = blockIdx.x * blockDim.x + threadIdx.x;
    if (i >= n) return;
    float h[CIN];
    h[0] = x[i];
    #pragma unroll
    for (int k = 1; k < CIN; ++k) h[k] = agg_in[(size_t)i * (CIN - 1) + (k - 1)];
    #pragma unroll
    for (int j = 0; j < COUT; ++j) {
        float q = 0.f;
        #pragma unroll
        for (int k = 0; k < CIN; ++k) q = fmaf(h[k], swn[k * COUT + j], q);
        Q[(size_t)i * PAD + j] = q;
    }
}

// pass 1 (4 threads/node): P-row on the fly; accumulate per-channel sum/sumsq
template<int CIN, int COUT, bool HASEA>
__global__ __launch_bounds__(BLK) void node_stats_kernel(
    const int* __restrict__ rowstart,
    const uint2* __restrict__ csr_e, const unsigned int* __restrict__ csr_psrc,
    const float* __restrict__ x, const float* __restrict__ agg_in,
    const float* __restrict__ ws, const float* __restrict__ Q,
    const float* __restrict__ we,
    double* __restrict__ stats, int N, int base, int koff)
{
    constexpr int PAD = (COUT + 3) & ~3;
    __shared__ float sws[CIN * COUT];
    for (int i = threadIdx.x; i < CIN * COUT; i += blockDim.x) sws[i] = ws[i];
    __syncthreads();
    float we0[COUT], we1[COUT];
    if constexpr (HASEA) {
        #pragma unroll
        for (int j = 0; j < COUT; ++j) { we0[j] = we[j]; we1[j] = we[COUT + j]; }
    }
    float s[COUT], ss[COUT];
    #pragma unroll
    for (int j = 0; j < COUT; ++j) { s[j] = 0.f; ss[j] = 0.f; }
    const int t = blockIdx.x * blockDim.x + threadIdx.x;
    const int i = t >> 2, quad = t & 3;
    if (i < N) {
        float h[CIN];
        h[0] = x[i];
        #pragma unroll
        for (int k = 1; k < CIN; ++k) h[k] = agg_in[(size_t)i * (CIN - 1) + (k - 1)];
        float pp[COUT];
        #pragma unroll
        for (int j = 0; j < COUT; ++j) {
            float p = 0.f;
            #pragma unroll
            for (int k = 0; k < CIN; ++k) p = fmaf(h[k], sws[k * COUT + j], p);
            pp[j] = p;
        }
        const int k0 = rowstart[base + i], k1 = rowstart[base + i + 1];
        for (int k = k0 + quad; k < k1; k += 4) {
            unsigned sn;
            float2 eav;
            if constexpr (HASEA) {
                const uint2 ce = csr_e[k];
                sn = ce.x; eav = unpack_ea(ce.y);
            } else {
                sn = csr_psrc[k - koff];
            }
            #pragma unroll
            for (int j = 0; j < COUT; ++j) {
                float m = pp[j] + Q[(size_t)sn * PAD + j];
                if constexpr (HASEA) m = fmaf(eav.x, we0[j], fmaf(eav.y, we1[j], m));
                s[j] += m; ss[j] = fmaf(m, m, ss[j]);
            }
        }
    }
    block_stats_reduce<COUT>(s, ss, stats);
}

// pass 2 (4 threads/node): BN+relu aggregate; optionally fuse next layer's Q projection
template<int CIN, int COUT, bool HASEA, int CIN2, int COUT2>
__global__ __launch_bounds__(BLK) void node_agg_kernel(
    const int* __restrict__ rowstart,
    const uint2* __restrict__ csr_e, const unsigned int* __restrict__ csr_psrc,
    const float* __restrict__ x, const float* __restrict__ agg_in,
    const float* __restrict__ ws, const float* __restrict__ Q,
    const float* __restrict__ we,
    const float* __restrict__ g, const float* __restrict__ b,
    const double* __restrict__ stats,
    float* __restrict__ agg_out,
    const float* __restrict__ wn2, float* __restrict__ Qout,
    int N, int base, int koff, float invE)
{
    constexpr int PAD = (COUT + 3) & ~3;
    constexpr bool FUSEQ = (COUT2 > 0);
    constexpr int W2 = FUSEQ ? CIN2 * COUT2 : 1;
    __shared__ float sws[CIN * COUT];
    __shared__ float swn2[W2];
    for (int i = threadIdx.x; i < CIN * COUT; i += blockDim.x) sws[i] = ws[i];
    if constexpr (FUSEQ) {
        for (int i = threadIdx.x; i < W2; i += blockDim.x) swn2[i] = wn2[i];
    }
    __syncthreads();
    const int t = blockIdx.x * blockDim.x + threadIdx.x;
    const int i = t >> 2, quad = t & 3;
    if (i >= N) return;
    float we0[COUT], we1[COUT];
    if constexpr (HASEA) {
        #pragma unroll
        for (int j = 0; j < COUT; ++j) { we0[j] = we[j]; we1[j] = we[COUT + j]; }
    }
    float sc[COUT], bb[COUT];
    bn_coefs<COUT>(stats, g, b, (double)invE, sc, bb);
    float h[CIN];
    h[0] = x[i];
    #pragma unroll
    for (int k = 1; k < CIN; ++k) h[k] = agg_in[(size_t)i * (CIN - 1) + (k - 1)];
    float pp[COUT], acc[COUT];
    #pragma unroll
    for (int j = 0; j < COUT; ++j) {
        float p = 0.f;
        #pragma unroll
        for (int k = 0; k < CIN; ++k) p = fmaf(h[k], sws[k * COUT + j], p);
        pp[j] = p; acc[j] = 0.f;
    }
    const int k0 = rowstart[base + i], k1 = rowstart[base + i + 1];
    for (int k = k0 + quad; k < k1; k += 4) {
        unsigned sn;
        float2 eav;
        if constexpr (HASEA) {
            const uint2 ce = csr_e[k];
            sn = ce.x; eav = unpack_ea(ce.y);
        } else {
            sn = csr_psrc[k - koff];
        }
        #pragma unroll
        for (int j = 0; j < COUT; ++j) {
            float m = pp[j] + Q[(size_t)sn * PAD + j];
            if constexpr (HASEA) m = fmaf(eav.x, we0[j], fmaf(eav.y, we1[j], m));
            acc[j] += fmaxf(fmaf(sc[j], m, bb[j]), 0.f);
        }
    }
    // butterfly: all 4 quad lanes end with the full row sum
    #pragma unroll
    for (int j = 0; j < COUT; ++j) {
        acc[j] += __shfl_xor(acc[j], 1, 64);
        acc[j] += __shfl_xor(acc[j], 2, 64);
    }
    if (quad == 0) {
        #pragma unroll
        for (int j = 0; j < COUT; ++j) agg_out[(size_t)i * COUT + j] = acc[j];
        if constexpr (FUSEQ) {
            constexpr int PAD2 = (COUT2 + 3) & ~3;
            #pragma unroll
            for (int j2 = 0; j2 < COUT2; ++j2) {
                float q = h[0] * swn2[j2];
                #pragma unroll
                for (int k = 0; k < COUT; ++k)
                    q = fmaf(acc[k], swn2[(k + 1) * COUT2 + j2], q);
                Qout[(size_t)i * PAD2 + j2] = q;
            }
        }
    }
}

// ============================ fallback (R1, atomic scatter) ============================

__global__ __launch_bounds__(BLK) void zero_stats_kernel(double* __restrict__ stats, int n)
{
    int i = blockIdx.x * blockDim.x + threadIdx.x;
    if (i < n) stats[i] = 0.0;
}

template<int CIN, int COUT>
__global__ __launch_bounds__(BLK) void projPQ_kernel(
    const float* __restrict__ x, const float* __restrict__ agg_in,
    const float* __restrict__ ws, const float* __restrict__ wn,
    float* __restrict__ P, float* __restrict__ Q, float* __restrict__ agg_out, int n)
{
    __shared__ float sws[CIN * COUT], swn[CIN * COUT];
    for (int i = threadIdx.x; i < CIN * COUT; i += blockDim.x) { sws[i] = ws[i]; swn[i] = wn[i]; }
    __syncthreads();
    const int i = blockIdx.x * blockDim.x + threadIdx.x;
    if (i >= n) return;
    float h[CIN];
    h[0] = x[i];
    #pragma unroll
    for (int k = 1; k < CIN; ++k) h[k] = agg_in[(size_t)i * (CIN - 1) + (k - 1)];
    #pragma unroll
    for (int j = 0; j < COUT; ++j) {
        float p = 0.f, q = 0.f;
        #pragma unroll
        for (int k = 0; k < CIN; ++k) {
            p = fmaf(h[k], sws[k * COUT + j], p);
            q = fmaf(h[k], swn[k * COUT + j], q);
        }
        P[(size_t)i * COUT + j] = p;
        Q[(size_t)i * COUT + j] = q;
        agg_out[(size_t)i * COUT + j] = 0.f;
    }
}

template<int COUT, bool HASEA>
__global__ __launch_bounds__(BLK) void edge_stats_kernel(
    const int* __restrict__ esrc, const int* __restrict__ edst,
    const float* __restrict__ P,  const float* __restrict__ Q,
    const float* __restrict__ ea, const float* __restrict__ we,
    double* __restrict__ stats, int E)
{
    float we0[COUT], we1[COUT];
    if constexpr (HASEA) {
        #pragma unroll
        for (int j = 0; j < COUT; ++j) { we0[j] = we[j]; we1[j] = we[COUT + j]; }
    }
    float s[COUT], ss[COUT];
    #pragma unroll
    for (int j = 0; j < COUT; ++j) { s[j] = 0.f; ss[j] = 0.f; }
    const int stride = gridDim.x * blockDim.x;
    for (int e = blockIdx.x * blockDim.x + threadIdx.x; e < E; e += stride) {
        const int d = edst[e], sn = esrc[e];
        float2 eav = make_float2(0.f, 0.f);
        if constexpr (HASEA) eav = ((const float2* __restrict__)ea)[e];
        #pragma unroll
        for (int j = 0; j < COUT; ++j) {
            float m = P[(size_t)d * COUT + j] + Q[(size_t)sn * COUT + j];
            if constexpr (HASEA) m += eav.x * we0[j] + eav.y * we1[j];
            s[j] += m; ss[j] = fmaf(m, m, ss[j]);
        }
    }
    block_stats_reduce<COUT>(s, ss, stats);
}

template<int COUT, bool HASEA>
__global__ __launch_bounds__(BLK) void edge_scatter_kernel(
    const int* __restrict__ esrc, const int* __restrict__ edst,
    const float* __restrict__ P,  const float* __restrict__ Q,
    const float* __restrict__ ea, const float* __restrict__ we,
    const float* __restrict__ g,  const float* __restrict__ b,
    const double* __restrict__ stats,
    float* __restrict__ agg_out, int E)
{
    float we0[COUT], we1[COUT], sc[COUT], bb[COUT];
    #pragma unroll
    for (int j = 0; j < COUT; ++j) {
        if constexpr (HASEA) { we0[j] = we[j]; we1[j] = we[COUT + j]; }
    }
    bn_coefs<COUT>(stats, g, b, 1.0 / (double)E, sc, bb);
    const int stride = gridDim.x * blockDim.x;
    for (int e = blockIdx.x * blockDim.x + threadIdx.x; e < E; e += stride) {
        const int d = edst[e], sn = esrc[e];
        float2 eav = make_float2(0.f, 0.f);
        if constexpr (HASEA) eav = ((const float2* __restrict__)ea)[e];
        #pragma unroll
        for (int j = 0; j < COUT; ++j) {
            float m = P[(size_t)d * COUT + j] + Q[(size_t)sn * COUT + j];
            if constexpr (HASEA) m += eav.x * we0[j] + eav.y * we1[j];
            const float y = fmaxf(fmaf(sc[j], m, bb[j]), 0.f);
            if (y > 0.f) unsafeAtomicAdd(&agg_out[(size_t)d * COUT + j], y);
        }
    }
}

// ============================ node MLP + edge head (shared) ============================

__global__ __launch_bounds__(BLK) void mlp1_kernel(
    const float* __restrict__ x, const float* __restrict__ agg6,
    const float* __restrict__ pw1, const float* __restrict__ pb1,
    float* __restrict__ t1, double* __restrict__ stats, int n)
{
    __shared__ float w[13 * 8];
    __shared__ float bsh[8];
    for (int i = threadIdx.x; i < 13 * 8; i += blockDim.x) w[i] = pw1[i];
    if (threadIdx.x < 8) bsh[threadIdx.x] = pb1[threadIdx.x];
    __syncthreads();
    const int i = blockIdx.x * blockDim.x + threadIdx.x;
    float s[8], ss[8];
    #pragma unroll
    for (int j = 0; j < 8; ++j) { s[j] = 0.f; ss[j] = 0.f; }
    if (i < n) {
        float h[13];
        h[0] = x[i];
        #pragma unroll
        for (int k = 0; k < 12; ++k) h[k + 1] = agg6[(size_t)i * 12 + k];
        #pragma unroll
        for (int j = 0; j < 8; ++j) {
            float t = bsh[j];
            #pragma unroll
            for (int k = 0; k < 13; ++k) t = fmaf(h[k], w[k * 8 + j], t);
            t = fmaxf(t, 0.f);
            t1[(size_t)i * 8 + j] = t;
            s[j] = t; ss[j] = t * t;
        }
    }
    block_stats_reduce<8>(s, ss, stats);
}

__global__ __launch_bounds__(BLK) void mlp2_kernel(
    const float* __restrict__ t1,
    const float* __restrict__ p1g, const float* __restrict__ p1b,
    const float* __restrict__ pw2, const float* __restrict__ pb2,
    const double* __restrict__ stats1,
    float* __restrict__ t2, double* __restrict__ stats2, int n)
{
    float sc[8], bb[8];
    bn_coefs<8>(stats1, p1g, p1b, 1.0 / (double)n, sc, bb);
    const int i = blockIdx.x * blockDim.x + threadIdx.x;
    float s[4], ss[4];
    #pragma unroll
    for (int j = 0; j < 4; ++j) { s[j] = 0.f; ss[j] = 0.f; }
    if (i < n) {
        float u[8];
        #pragma unroll
        for (int j = 0; j < 8; ++j) u[j] = fmaf(sc[j], t1[(size_t)i * 8 + j], bb[j]);
        #pragma unroll
        for (int j2 = 0; j2 < 4; ++j2) {
            float t = pb2[j2];
            #pragma unroll
            for (int j = 0; j < 8; ++j) t = fmaf(u[j], pw2[j * 4 + j2], t);
            t = fmaxf(t, 0.f);
            t2[(size_t)i * 4 + j2] = t;
            s[j2] = t; ss[j2] = t * t;
        }
    }
    block_stats_reduce<4>(s, ss, stats2);
}

__global__ __launch_bounds__(BLK) void mlp3_kernel(
    const float* __restrict__ t2,
    const float* __restrict__ p2g, const float* __restrict__ p2b,
    const float* __restrict__ pw3, const float* __restrict__ pb3,
    const float* __restrict__ x, const float* __restrict__ agg6,
    const float* __restrict__ ew1, const float* __restrict__ eb1,
    const double* __restrict__ stats2,
    float* __restrict__ power_out, float* __restrict__ A, float* __restrict__ B,
    int n, int astride)
{
    __shared__ float w1[28 * 14];
    for (int i = threadIdx.x; i < 28 * 14; i += blockDim.x) w1[i] = ew1[i];
    __syncthreads();
    float sc[4], bb[4];
    bn_coefs<4>(stats2, p2g, p2b, 1.0 / (double)n, sc, bb);
    const int i = blockIdx.x * blockDim.x + threadIdx.x;
    if (i >= n) return;
    float z = pb3[0];
    #pragma unroll
    for (int j = 0; j < 4; ++j) z = fmaf(fmaf(sc[j], t2[(size_t)i * 4 + j], bb[j]), pw3[j], z);
    const float pw = sigmoid15(z);
    power_out[i] = pw;
    float h[14];
    h[0] = x[i];
    #pragma unroll
    for (int k = 0; k < 12; ++k) h[k + 1] = agg6[(size_t)i * 12 + k];
    h[13] = pw;
    #pragma unroll
    for (int c = 0; c < 14; ++c) {
        float a = eb1[c], b2 = 0.f;
        #pragma unroll
        for (int k = 0; k < 14; ++k) {
            a  = fmaf(h[k], w1[k * 14 + c], a);
            b2 = fmaf(h[k], w1[(14 + k) * 14 + c], b2);
        }
        A[(size_t)i * astride + c] = a;
        B[(size_t)i * astride + c] = b2;
    }
}

__global__ __launch_bounds__(BLK) void ehead_stats_kernel(
    const int* __restrict__ dsrc, const int* __restrict__ ddst,
    const float* __restrict__ A, const float* __restrict__ B,
    double* __restrict__ stats, int E, int astride)
{
    float s[14], ss[14];
    #pragma unroll
    for (int j = 0; j < 14; ++j) { s[j] = 0.f; ss[j] = 0.f; }
    const int stride = gridDim.x * blockDim.x;
    for (int e = blockIdx.x * blockDim.x + threadIdx.x; e < E; e += stride) {
        const int dd = ddst[e], ds = dsrc[e];
        #pragma unroll
        for (int c = 0; c < 14; ++c) {
            const float r = fmaxf(A[(size_t)dd * astride + c] + B[(size_t)ds * astride + c], 0.f);
            s[c] += r; ss[c] = fmaf(r, r, ss[c]);
        }
    }
    block_stats_reduce<14>(s, ss, stats);
}

__global__ __launch_bounds__(BLK) void ehead_final_kernel(
    const int* __restrict__ dsrc, const int* __restrict__ ddst,
    const float* __restrict__ A, const float* __restrict__ B,
    const float* __restrict__ e1g, const float* __restrict__ e1b,
    const float* __restrict__ ew2, const float* __restrict__ eb2,
    const double* __restrict__ stats, float* __restrict__ dir_out, int E, int astride)
{
    float sc[14];
    float off = eb2[0];
    const double invE = 1.0 / (double)E;
    #pragma unroll
    for (int c = 0; c < 14; ++c) {
        const double mu  = stats[c] * invE;
        const double var = stats[16 + c] * invE - mu * mu;
        const float inv = rsqrtf((float)(var + (double)BN_EPS));
        const float gi = e1g[c] * inv;
        sc[c] = gi * ew2[c];
        off += (e1b[c] - (float)mu * gi) * ew2[c];
    }
    const int stride = gridDim.x * blockDim.x;
    for (int e = blockIdx.x * blockDim.x + threadIdx.x; e < E; e += stride) {
        const int dd = ddst[e], ds = dsrc[e];
        float z = off;
        #pragma unroll
        for (int c = 0; c < 14; ++c) {
            const float r = fmaxf(A[(size_t)dd * astride + c] + B[(size_t)ds * astride + c], 0.f);
            z = fmaf(r, sc[c], z);
        }
        dir_out[e] = sigmoid15(z);
    }
}

// ============================ launch ============================

extern "C" void kernel_launch(void* const* d_in, const int* in_sizes, int n_in,
                              void* d_out, int out_size, void* d_ws, size_t ws_size,
                              hipStream_t stream)
{
    const float* x    = (const float*)d_in[0];
    const float* ea   = (const float*)d_in[1];
    const int*   eidx = (const int*)d_in[2];
    const int*   didx = (const int*)d_in[3];
    const int*   pidx = (const int*)d_in[4];
    const float *c1_ws=(const float*)d_in[5],  *c1_wn=(const float*)d_in[6],  *c1_we=(const float*)d_in[7],  *c1_g=(const float*)d_in[8],  *c1_b=(const float*)d_in[9];
    const float *d1_ws=(const float*)d_in[10], *d1_wn=(const float*)d_in[11], *d1_g=(const float*)d_in[12], *d1_b=(const float*)d_in[13];
    const float *c2_ws=(const float*)d_in[14], *c2_wn=(const float*)d_in[15], *c2_we=(const float*)d_in[16], *c2_g=(const float*)d_in[17], *c2_b=(const float*)d_in[18];
    const float *d2_ws=(const float*)d_in[19], *d2_wn=(const float*)d_in[20], *d2_g=(const float*)d_in[21], *d2_b=(const float*)d_in[22];
    const float *c3_ws=(const float*)d_in[23], *c3_wn=(const float*)d_in[24], *c3_we=(const float*)d_in[25], *c3_g=(const float*)d_in[26], *c3_b=(const float*)d_in[27];
    const float *d3_ws=(const float*)d_in[28], *d3_wn=(const float*)d_in[29], *d3_g=(const float*)d_in[30], *d3_b=(const float*)d_in[31];
    const float *pw1=(const float*)d_in[32], *pb1=(const float*)d_in[33], *p1_g=(const float*)d_in[34], *p1_b=(const float*)d_in[35];
    const float *pw2=(const float*)d_in[36], *pb2=(const float*)d_in[37], *p2_g=(const float*)d_in[38], *p2_b=(const float*)d_in[39];
    const float *pw3=(const float*)d_in[40], *pb3=(const float*)d_in[41];
    const float *ew1=(const float*)d_in[42], *eb1=(const float*)d_in[43], *e1_g=(const float*)d_in[44], *e1_b=(const float*)d_in[45];
    const float *ew2=(const float*)d_in[46], *eb2=(const float*)d_in[47];

    const int N = in_sizes[0];
    const int E = in_sizes[2] / 2;
    const int n2 = 2 * N;
    const int *esrc = eidx,     *edst = eidx + E;
    const int *dsrc = didx,     *ddst = didx + E;
    const int *psrc = pidx,     *pdst = pidx + E;

    float* power_out = (float*)d_out;
    float* dir_out   = power_out + N;

    const int gN  = (N + BLK - 1) / BLK;
    const int g2  = (n2 + BLK - 1) / BLK;
    const int g4  = ((size_t)4 * N + BLK - 1) / BLK;   // 4 threads/node
    const int gE  = 1024;                              // reduction kernels
    const int gEf = (E + BLK - 1) / BLK;               // full streaming grid
    const int gX  = 8 * 160;                           // 8 XCD groups x 160 blocks
    const float invE = 1.0f / (float)E;

    // ---- CSR-path workspace need (~40.1 MB) ----
    const size_t abFloats = (size_t)32 * N;            // A/B tables reuse csr_e region
    const size_t csreBytes = ((size_t)8 * E > 4 * abFloats) ? (size_t)8 * E : 4 * abFloats;
    const size_t need_csr = 4096
        + sizeof(float) * ((size_t)N * 12   /* Qa   */
                         + (size_t)N * 12   /* Qb   */
                         + (size_t)N * 12   /* aggA */
                         + (size_t)N * 12)  /* aggB */
        + csreBytes                         /* csr_e (uint2) / A,B */
        + sizeof(unsigned int) * (size_t)E  /* csr_psrc */
        + sizeof(int) * ((size_t)n2 + 2)    /* rowstart */
        + sizeof(int) * (size_t)n2          /* cursor(=deg) */
        + sizeof(int) * 1024;               /* partials */

    double* stats = (double*)d_ws;                     // 288 doubles

    if (ws_size >= need_csr) {
        // ================= CSR gather path =================
        float* fws  = (float*)((char*)d_ws + 4096);
        float* Qa   = fws;                fws += (size_t)N * 12;
        float* Qb   = fws;                fws += (size_t)N * 12;
        float* aggA = fws;                fws += (size_t)N * 12;
        float* aggB = fws;                fws += (size_t)N * 12;
        uint2* csr_e = (uint2*)fws;
        unsigned int* csr_psrc = (unsigned int*)((char*)csr_e + csreBytes);
        int* rowstart = (int*)(csr_psrc + E);
        int* cursor   = rowstart + (n2 + 2);           // aliases deg
        int* deg      = cursor;
        int* partials = cursor + n2;
        float* t1   = aggA;                             // aggA free after conv stack
        float* t2   = aggA + (size_t)N * 8;
        float* Abuf = (float*)csr_e;                    // csr_e dead after conv stack
        float* Bbuf = Abuf + (size_t)N * 16;

        const int nparts = (n2 + 1023) / 1024;

        init_kernel<<<g2, BLK, 0, stream>>>(deg, stats, rowstart, n2, 2 * E);
        hist_kernel<<<gX, BLK, 0, stream>>>(edst, pdst, deg, N, E);
        scan1_kernel<<<nparts, 256, 0, stream>>>(deg, rowstart, partials, n2);
        scan2_kernel<<<1, 256, 0, stream>>>(partials, nparts);
        scan3_kernel<<<g2, BLK, 0, stream>>>(rowstart, cursor, partials, n2);
        fill_kernel<<<gX, BLK, 0, stream>>>(esrc, edst, psrc, pdst, ea, cursor, csr_e, csr_psrc, N, E);

        // L0: c1 (1->2, EA); agg fused with projQ for L1 (CIN2=3, COUT2=4)
        projQ_kernel<1, 2><<<gN, BLK, 0, stream>>>(x, nullptr, c1_wn, Qa, N);
        node_stats_kernel<1, 2, true><<<g4, BLK, 0, stream>>>(rowstart, csr_e, csr_psrc, x, nullptr, c1_ws, Qa, c1_we, stats + 0, N, 0, 0);
        node_agg_kernel<1, 2, true, 3, 4><<<g4, BLK, 0, stream>>>(rowstart, csr_e, csr_psrc, x, nullptr, c1_ws, Qa, c1_we, c1_g, c1_b, stats + 0, aggA, d1_wn, Qb, N, 0, 0, invE);
        // L1: d1 (3->4, prop); fused projQ for L2 (5,6)
        node_stats_kernel<3, 4, false><<<g4, BLK, 0, stream>>>(rowstart, csr_e, csr_psrc, x, aggA, d1_ws, Qb, nullptr, stats + 32, N, N, E);
        node_agg_kernel<3, 4, false, 5, 6><<<g4, BLK, 0, stream>>>(rowstart, csr_e, csr_psrc, x, aggA, d1_ws, Qb, nullptr, d1_g, d1_b, stats + 32, aggB, c2_wn, Qa, N, N, E, invE);
        // L2: c2 (5->6, EA); fused projQ for L3 (7,8)
        node_stats_kernel<5, 6, true><<<g4, BLK, 0, stream>>>(rowstart, csr_e, csr_psrc, x, aggB, c2_ws, Qa, c2_we, stats + 64, N, 0, 0);
        node_agg_kernel<5, 6, true, 7, 8><<<g4, BLK, 0, stream>>>(rowstart, csr_e, csr_psrc, x, aggB, c2_ws, Qa, c2_we, c2_g, c2_b, stats + 64, aggA, d2_wn, Qb, N, 0, 0, invE);
        // L3: d2 (7->8, prop); fused projQ for L4 (9,10)
        node_stats_kernel<7, 8, false><<<g4, BLK, 0, stream>>>(rowstart, csr_e, csr_psrc, x, aggA, d2_ws, Qb, nullptr, stats + 96, N, N, E);
        node_agg_kernel<7, 8, false, 9, 10><<<g4, BLK, 0, stream>>>(rowstart, csr_e, csr_psrc, x, aggA, d2_ws, Qb, nullptr, d2_g, d2_b, stats + 96, aggB, c3_wn, Qa, N, N, E, invE);
        // L4: c3 (9->10, EA); fused projQ for L5 (11,12)
        node_stats_kernel<9, 10, true><<<g4, BLK, 0, stream>>>(rowstart, csr_e, csr_psrc, x, aggB, c3_ws, Qa, c3_we, stats + 128, N, 0, 0);
        node_agg_kernel<9, 10, true, 11, 12><<<g4, BLK, 0, stream>>>(rowstart, csr_e, csr_psrc, x, aggB, c3_ws, Qa, c3_we, c3_g, c3_b, stats + 128, aggA, d3_wn, Qb, N, 0, 0, invE);
        // L5: d3 (11->12, prop); no fuse
        node_stats_kernel<11, 12, false><<<g4, BLK, 0, stream>>>(rowstart, csr_e, csr_psrc, x, aggA, d3_ws, Qb, nullptr, stats + 160, N, N, E);
        node_agg_kernel<11, 12, false, 0, 0><<<g4, BLK, 0, stream>>>(rowstart, csr_e, csr_psrc, x, aggA, d3_ws, Qb, nullptr, d3_g, d3_b, stats + 160, aggB, nullptr, nullptr, N, N, E, invE);

        mlp1_kernel<<<gN, BLK, 0, stream>>>(x, aggB, pw1, pb1, t1, stats + 192, N);
        mlp2_kernel<<<gN, BLK, 0, stream>>>(t1, p1_g, p1_b, pw2, pb2, stats + 192, t2, stats + 224, N);
        mlp3_kernel<<<gN, BLK, 0, stream>>>(t2, p2_g, p2_b, pw3, pb3, x, aggB, ew1, eb1, stats + 224,
                                            power_out, Abuf, Bbuf, N, 16);
        ehead_stats_kernel<<<gE, BLK, 0, stream>>>(dsrc, ddst, Abuf, Bbuf, stats + 256, E, 16);
        ehead_final_kernel<<<gEf, BLK, 0, stream>>>(dsrc, ddst, Abuf, Bbuf, e1_g, e1_b, ew2, eb2,
                                                    stats + 256, dir_out, E, 16);
    } else {
        // ================= fallback: R1 atomic-scatter path (20.8 MB, proven) =================
        float* fws  = (float*)((char*)d_ws + 4096);
        float* P    = fws;                fws += (size_t)N * 14;
        float* Q    = fws;                fws += (size_t)N * 14;
        float* aggA = fws;                fws += (size_t)N * 12;
        float* aggB = fws;                fws += (size_t)N * 12;
        float* t1   = aggA;
        float* t2   = aggA + (size_t)N * 8;
        float* Abuf = P;                  // stride 14
        float* Bbuf = Q;

        zero_stats_kernel<<<2, BLK, 0, stream>>>(stats, 288);

        projPQ_kernel<1, 2><<<gN, BLK, 0, stream>>>(x, nullptr, c1_ws, c1_wn, P, Q, aggA, N);
        edge_stats_kernel<2, true><<<gE, BLK, 0, stream>>>(esrc, edst, P, Q, ea, c1_we, stats + 0, E);
        edge_scatter_kernel<2, true><<<gE, BLK, 0, stream>>>(esrc, edst, P, Q, ea, c1_we, c1_g, c1_b, stats + 0, aggA, E);

        projPQ_kernel<3, 4><<<gN, BLK, 0, stream>>>(x, aggA, d1_ws, d1_wn, P, Q, aggB, N);
        edge_stats_kernel<4, false><<<gE, BLK, 0, stream>>>(psrc, pdst, P, Q, nullptr, nullptr, stats + 32, E);
        edge_scatter_kernel<4, false><<<gE, BLK, 0, stream>>>(psrc, pdst, P, Q, nullptr, nullptr, d1_g, d1_b, stats + 32, aggB, E);

        projPQ_kernel<5, 6><<<gN, BLK, 0, stream>>>(x, aggB, c2_ws, c2_wn, P, Q, aggA, N);
        edge_stats_kernel<6, true><<<gE, BLK, 0, stream>>>(esrc, edst, P, Q, ea, c2_we, stats + 64, E);
        edge_scatter_kernel<6, true><<<gE, BLK, 0, stream>>>(esrc, edst, P, Q, ea, c2_we, c2_g, c2_b, stats + 64, aggA, E);

        projPQ_kernel<7, 8><<<gN, BLK, 0, stream>>>(x, aggA, d2_ws, d2_wn, P, Q, aggB, N);
        edge_stats_kernel<8, false><<<gE, BLK, 0, stream>>>(psrc, pdst, P, Q, nullptr, nullptr, stats + 96, E);
        edge_scatter_kernel<8, false><<<gE, BLK, 0, stream>>>(psrc, pdst, P, Q, nullptr, nullptr, d2_g, d2_b, stats + 96, aggB, E);

        projPQ_kernel<9, 10><<<gN, BLK, 0, stream>>>(x, aggB, c3_ws, c3_wn, P, Q, aggA, N);
        edge_stats_kernel<10, true><<<gE, BLK, 0, stream>>>(esrc, edst, P, Q, ea, c3_we, stats + 128, E);
        edge_scatter_kernel<10, true><<<gE, BLK, 0, stream>>>(esrc, edst, P, Q, ea, c3_we, c3_g, c3_b, stats + 128, aggA, E);

        projPQ_kernel<11, 12><<<gN, BLK, 0, stream>>>(x, aggA, d3_ws, d3_wn, P, Q, aggB, N);
        edge_stats_kernel<12, false><<<gE, BLK, 0, stream>>>(psrc, pdst, P, Q, nullptr, nullptr, stats + 160, E);
        edge_scatter_kernel<12, false><<<gE, BLK, 0, stream>>>(psrc, pdst, P, Q, nullptr, nullptr, d3_g, d3_b, stats + 160, aggB, E);

        mlp1_kernel<<<gN, BLK, 0, stream>>>(x, aggB, pw1, pb1, t1, stats + 192, N);
        mlp2_kernel<<<gN, BLK, 0, stream>>>(t1, p1_g, p1_b, pw2, pb2, stats + 192, t2, stats + 224, N);
        mlp3_kernel<<<gN, BLK, 0, stream>>>(t2, p2_g, p2_b, pw3, pb3, x, aggB, ew1, eb1, stats + 224,
                                            power_out, Abuf, Bbuf, N, 14);
        ehead_stats_kernel<<<gE, BLK, 0, stream>>>(dsrc, ddst, Abuf, Bbuf, stats + 256, E, 14);
        ehead_final_kernel<<<gE, BLK, 0, stream>>>(dsrc, ddst, Abuf, Bbuf, e1_g, e1_b, ew2, eb2,
                                                   stats + 256, dir_out, E, 14);
    }
}

// Round 10
// 892.249 us; speedup vs baseline: 1.2225x; 1.0671x over previous
//
#include <hip/hip_runtime.h>
#include <hip/hip_fp16.h>
#include <math.h>

static constexpr int BLK = 256;   // 4 waves of 64
static constexpr float BN_EPS = 1e-5f;

__device__ __forceinline__ float sigmoid15(float z) {
    return 1.0f / (1.0f + expf(-1.5f * z));
}

__device__ __forceinline__ unsigned pack_ea(float2 v) {
    unsigned hx = __half_as_ushort(__float2half_rn(v.x));
    unsigned hy = __half_as_ushort(__float2half_rn(v.y));
    return hx | (hy << 16);
}
__device__ __forceinline__ float2 unpack_ea(unsigned u) {
    return make_float2(__half2float(__ushort_as_half((unsigned short)(u & 0xffffu))),
                       __half2float(__ushort_as_half((unsigned short)(u >> 16))));
}

__host__ __device__ constexpr int padh(int c) { return (c <= 8) ? 8 : 16; }

// load a padded fp16 row -> float regs (1-2 x 16B vector loads)  [plain loads: rows are
// produced by earlier kernels in this launch — NO nontemporal on workspace]
template<int C>
__device__ __forceinline__ void load_hrow(const __half* __restrict__ T, size_t row, float (&q)[C])
{
    constexpr int PADH = padh(C);
    const uint4* p = (const uint4*)(T + row * PADH);
    unsigned w[PADH / 2];
    uint4 r0 = p[0];
    w[0] = r0.x; w[1] = r0.y; w[2] = r0.z; w[3] = r0.w;
    if constexpr (C > 8) { uint4 r1 = p[1]; w[4] = r1.x; w[5] = r1.y; w[6] = r1.z; w[7] = r1.w; }
    #pragma unroll
    for (int j = 0; j < C; ++j) {
        unsigned h = (w[j >> 1] >> ((j & 1) * 16)) & 0xffffu;
        q[j] = __half2float(__ushort_as_half((unsigned short)h));
    }
}

// store float regs -> padded fp16 row
template<int C>
__device__ __forceinline__ void store_hrow(__half* __restrict__ T, size_t row, const float (&q)[C])
{
    constexpr int PADH = padh(C);
    unsigned w[PADH / 2] = {0};
    #pragma unroll
    for (int j = 0; j < C; ++j) {
        unsigned h = __half_as_ushort(__float2half_rn(q[j]));
        w[j >> 1] |= h << ((j & 1) * 16);
    }
    uint4* p = (uint4*)(T + row * PADH);
    p[0] = make_uint4(w[0], w[1], w[2], w[3]);
    if constexpr (C > 8) p[1] = make_uint4(w[4], w[5], w[6], w[7]);
}

// -------- block-level per-channel (sum, sumsq) reduction into double stats --------
template<int C>
__device__ __forceinline__ void block_stats_reduce(float (&s)[C], float (&ss)[C],
                                                   double* __restrict__ stats)
{
    #pragma unroll
    for (int j = 0; j < C; ++j) {
        #pragma unroll
        for (int o = 32; o > 0; o >>= 1) {
            s[j]  += __shfl_down(s[j],  o, 64);
            ss[j] += __shfl_down(ss[j], o, 64);
        }
    }
    __shared__ float red[2][C][BLK / 64];
    const int wave = threadIdx.x >> 6, lane = threadIdx.x & 63;
    if (lane == 0) {
        #pragma unroll
        for (int j = 0; j < C; ++j) { red[0][j][wave] = s[j]; red[1][j][wave] = ss[j]; }
    }
    __syncthreads();
    if (threadIdx.x < C) {
        const int j = threadIdx.x;
        float a = 0.f, b = 0.f;
        #pragma unroll
        for (int w = 0; w < BLK / 64; ++w) { a += red[0][j][w]; b += red[1][j][w]; }
        atomicAdd(&stats[j],      (double)a);
        atomicAdd(&stats[16 + j], (double)b);
    }
}

template<int C>
__device__ __forceinline__ void bn_coefs(const double* __restrict__ stats,
                                         const float* __restrict__ g, const float* __restrict__ b,
                                         double invE, float (&sc)[C], float (&bb)[C])
{
    #pragma unroll
    for (int j = 0; j < C; ++j) {
        const double mu  = stats[j] * invE;
        const double var = stats[16 + j] * invE - mu * mu;
        const float inv = rsqrtf((float)(var + (double)BN_EPS));
        const float gg = g[j];
        sc[j] = gg * inv;
        bb[j] = b[j] - (float)mu * gg * inv;
    }
}

// ============================ CSR build (CSR path) ============================

__global__ __launch_bounds__(BLK) void init_kernel(int* __restrict__ deg, double* __restrict__ stats,
                                                   int* __restrict__ rowstart, int n2, int total)
{
    const int i = blockIdx.x * blockDim.x + threadIdx.x;
    if (i < n2) deg[i] = 0;
    if (i < 288) stats[i] = 0.0;
    if (i == 0) rowstart[n2] = total;
}

// XCD-range-partitioned histogram (nt loads OK: d_in streams only)
__global__ __launch_bounds__(BLK) void hist_kernel(const int* __restrict__ edst,
                                                   const int* __restrict__ pdst,
                                                   int* __restrict__ deg, int N, int E)
{
    const int grp = blockIdx.x & 7;
    const int bg  = blockIdx.x >> 3;
    const int gstride = (gridDim.x >> 3) * blockDim.x;
    if (grp < 4) {
        const int lo = (int)((size_t)N * grp / 4), hi = (int)((size_t)N * (grp + 1) / 4);
        for (int e = bg * blockDim.x + threadIdx.x; e < E; e += gstride) {
            const int d = __builtin_nontemporal_load(&edst[e]);
            if (d >= lo && d < hi) atomicAdd(&deg[d], 1);
        }
    } else {
        const int gg = grp - 4;
        const int lo = (int)((size_t)N * gg / 4), hi = (int)((size_t)N * (gg + 1) / 4);
        for (int e = bg * blockDim.x + threadIdx.x; e < E; e += gstride) {
            const int p = __builtin_nontemporal_load(&pdst[e]);
            if (p >= lo && p < hi) atomicAdd(&deg[N + p], 1);
        }
    }
}

__global__ __launch_bounds__(256) void scan1_kernel(const int* __restrict__ deg,
                                                    int* __restrict__ rowstart,
                                                    int* __restrict__ partials, int n2)
{
    __shared__ int lds[256];
    const int tid = threadIdx.x;
    const int base = blockIdx.x * 1024 + tid * 4;
    int v[4]; int loc = 0;
    #pragma unroll
    for (int r = 0; r < 4; ++r) { v[r] = (base + r < n2) ? deg[base + r] : 0; loc += v[r]; }
    lds[tid] = loc; __syncthreads();
    #pragma unroll
    for (int off = 1; off < 256; off <<= 1) {
        int t = (tid >= off) ? lds[tid - off] : 0;
        __syncthreads();
        lds[tid] += t;
        __syncthreads();
    }
    int excl = lds[tid] - loc;
    int run = excl;
    #pragma unroll
    for (int r = 0; r < 4; ++r) {
        if (base + r < n2) rowstart[base + r] = run;
        run += v[r];
    }
    if (tid == 255) partials[blockIdx.x] = lds[255];
}

__global__ __launch_bounds__(256) void scan2_kernel(int* __restrict__ partials, int n)
{
    __shared__ int lds[256];
    const int tid = threadIdx.x;
    const int base = tid * 4;
    int v[4]; int loc = 0;
    #pragma unroll
    for (int r = 0; r < 4; ++r) { v[r] = (base + r < n) ? partials[base + r] : 0; loc += v[r]; }
    lds[tid] = loc; __syncthreads();
    #pragma unroll
    for (int off = 1; off < 256; off <<= 1) {
        int t = (tid >= off) ? lds[tid - off] : 0;
        __syncthreads();
        lds[tid] += t;
        __syncthreads();
    }
    int excl = lds[tid] - loc;
    int run = excl;
    #pragma unroll
    for (int r = 0; r < 4; ++r) {
        if (base + r < n) partials[base + r] = run;
        run += v[r];
    }
}

__global__ __launch_bounds__(BLK) void scan3_kernel(int* __restrict__ rowstart,
                                                    int* __restrict__ cursor,
                                                    const int* __restrict__ partials, int n2)
{
    const int i = blockIdx.x * blockDim.x + threadIdx.x;
    if (i >= n2) return;
    const int v = rowstart[i] + partials[i >> 10];
    rowstart[i] = v;
    cursor[i] = v;
}

// XCD-range-partitioned fill (nt loads on d_in streams only)
__global__ __launch_bounds__(BLK) void fill_kernel(
    const int* __restrict__ esrc, const int* __restrict__ edst,
    const int* __restrict__ psrc, const int* __restrict__ pdst,
    const float* __restrict__ ea,
    int* __restrict__ cursor, uint2* __restrict__ csr_e,
    unsigned int* __restrict__ csr_psrc, int N, int E)
{
    const int grp = blockIdx.x & 7;
    const int bg  = blockIdx.x >> 3;
    const int gstride = (gridDim.x >> 3) * blockDim.x;
    if (grp < 4) {
        const int lo = (int)((size_t)N * grp / 4), hi = (int)((size_t)N * (grp + 1) / 4);
        for (int e = bg * blockDim.x + threadIdx.x; e < E; e += gstride) {
            const int d = __builtin_nontemporal_load(&edst[e]);
            if (d >= lo && d < hi) {
                const double eabits = __builtin_nontemporal_load((const double*)ea + e);
                float2 eav; __builtin_memcpy(&eav, &eabits, 8);
                const int sn = __builtin_nontemporal_load(&esrc[e]);
                const int pos = atomicAdd(&cursor[d], 1);
                csr_e[pos] = make_uint2((unsigned)sn, pack_ea(eav));
            }
        }
    } else {
        const int gg = grp - 4;
        const int lo = (int)((size_t)N * gg / 4), hi = (int)((size_t)N * (gg + 1) / 4);
        for (int e = bg * blockDim.x + threadIdx.x; e < E; e += gstride) {
            const int p = __builtin_nontemporal_load(&pdst[e]);
            if (p >= lo && p < hi) {
                const int sn = __builtin_nontemporal_load(&psrc[e]);
                const int pos2 = atomicAdd(&cursor[N + p], 1);
                csr_psrc[pos2 - E] = (unsigned)sn;
            }
        }
    }
}

// ============================ CSR-path layer kernels ============================

// Q projection (standalone for L0 only), fp16 output
template<int CIN, int COUT>
__global__ __launch_bounds__(BLK) void projQ_kernel(
    const float* __restrict__ x, const float* __restrict__ agg_in,
    const float* __restrict__ wn, __half* __restrict__ Q, int n)
{
    __shared__ float swn[CIN * COUT];
    for (int i = threadIdx.x; i < CIN * COUT; i += blockDim.x) swn[i] = wn[i];
    __syncthreads();
    const int i = blockIdx.x * blockDim.x + threadIdx.x;
    if (i >= n) return;
    float h[CIN];
    h[0] = x[i];
    #pragma unroll
    for (int k = 1; k < CIN; ++k) h[k] = agg_in[(size_t)i * (CIN - 1) + (k - 1)];
    float q[COUT];
    #pragma unroll
    for (int j = 0; j < COUT; ++j) {
        float qq = 0.f;
        #pragma unroll
        for (int k = 0; k < CIN; ++k) qq = fmaf(h[k], swn[k * COUT + j], qq);
        q[j] = qq;
    }
    store_hrow<COUT>(Q, (size_t)i, q);
}

// pass 1 (4 threads/node): P-row on the fly; accumulate per-channel sum/sumsq
// csr_e / csr_psrc read with PLAIN loads (workspace written this launch).
template<int CIN, int COUT, bool HASEA>
__global__ __launch_bounds__(BLK) void node_stats_kernel(
    const int* __restrict__ rowstart,
    const uint2* __restrict__ csr_e, const unsigned int* __restrict__ csr_psrc,
    const float* __restrict__ x, const float* __restrict__ agg_in,
    const float* __restrict__ ws, const __half* __restrict__ Q,
    const float* __restrict__ we,
    double* __restrict__ stats, int N, int base, int koff)
{
    __shared__ float sws[CIN * COUT];
    for (int i = threadIdx.x; i < CIN * COUT; i += blockDim.x) sws[i] = ws[i];
    __syncthreads();
    float we0[COUT], we1[COUT];
    if constexpr (HASEA) {
        #pragma unroll
        for (int j = 0; j < COUT; ++j) { we0[j] = we[j]; we1[j] = we[COUT + j]; }
    }
    float s[COUT], ss[COUT];
    #pragma unroll
    for (int j = 0; j < COUT; ++j) { s[j] = 0.f; ss[j] = 0.f; }
    const int t = blockIdx.x * blockDim.x + threadIdx.x;
    const int i = t >> 2, quad = t & 3;
    if (i < N) {
        float h[CIN];
        h[0] = x[i];
        #pragma unroll
        for (int k = 1; k < CIN; ++k) h[k] = agg_in[(size_t)i * (CIN - 1) + (k - 1)];
        float pp[COUT];
        #pragma unroll
        for (int j = 0; j < COUT; ++j) {
            float p = 0.f;
            #pragma unroll
            for (int k = 0; k < CIN; ++k) p = fmaf(h[k], sws[k * COUT + j], p);
            pp[j] = p;
        }
        const int k0 = rowstart[base + i], k1 = rowstart[base + i + 1];
        for (int k = k0 + quad; k < k1; k += 4) {
            unsigned sn;
            float2 eav;
            if constexpr (HASEA) {
                const uint2 ce = csr_e[k];
                sn = ce.x; eav = unpack_ea(ce.y);
            } else {
                sn = csr_psrc[k - koff];
            }
            float qr[COUT];
            load_hrow<COUT>(Q, (size_t)sn, qr);
            #pragma unroll
            for (int j = 0; j < COUT; ++j) {
                float m = pp[j] + qr[j];
                if constexpr (HASEA) m = fmaf(eav.x, we0[j], fmaf(eav.y, we1[j], m));
                s[j] += m; ss[j] = fmaf(m, m, ss[j]);
            }
        }
    }
    block_stats_reduce<COUT>(s, ss, stats);
}

// pass 2 (4 threads/node): BN+relu aggregate; optional fused next-layer Q projection (fp16)
template<int CIN, int COUT, bool HASEA, int CIN2, int COUT2>
__global__ __launch_bounds__(BLK) void node_agg_kernel(
    const int* __restrict__ rowstart,
    const uint2* __restrict__ csr_e, const unsigned int* __restrict__ csr_psrc,
    const float* __restrict__ x, const float* __restrict__ agg_in,
    const float* __restrict__ ws, const __half* __restrict__ Q,
    const float* __restrict__ we,
    const float* __restrict__ g, const float* __restrict__ b,
    const double* __restrict__ stats,
    float* __restrict__ agg_out,
    const float* __restrict__ wn2, __half* __restrict__ Qout,
    int N, int base, int koff, float invE)
{
    constexpr bool FUSEQ = (COUT2 > 0);
    constexpr int W2 = FUSEQ ? CIN2 * COUT2 : 1;
    __shared__ float sws[CIN * COUT];
    __shared__ float swn2[W2];
    for (int i = threadIdx.x; i < CIN * COUT; i += blockDim.x) sws[i] = ws[i];
    if constexpr (FUSEQ) {
        for (int i = threadIdx.x; i < W2; i += blockDim.x) swn2[i] = wn2[i];
    }
    __syncthreads();
    const int t = blockIdx.x * blockDim.x + threadIdx.x;
    const int i = t >> 2, quad = t & 3;
    if (i >= N) return;
    float we0[COUT], we1[COUT];
    if constexpr (HASEA) {
        #pragma unroll
        for (int j = 0; j < COUT; ++j) { we0[j] = we[j]; we1[j] = we[COUT + j]; }
    }
    float sc[COUT], bb[COUT];
    bn_coefs<COUT>(stats, g, b, (double)invE, sc, bb);
    float h[CIN];
    h[0] = x[i];
    #pragma unroll
    for (int k = 1; k < CIN; ++k) h[k] = agg_in[(size_t)i * (CIN - 1) + (k - 1)];
    float pp[COUT], acc[COUT];
    #pragma unroll
    for (int j = 0; j < COUT; ++j) {
        float p = 0.f;
        #pragma unroll
        for (int k = 0; k < CIN; ++k) p = fmaf(h[k], sws[k * COUT + j], p);
        pp[j] = p; acc[j] = 0.f;
    }
    const int k0 = rowstart[base + i], k1 = rowstart[base + i + 1];
    for (int k = k0 + quad; k < k1; k += 4) {
        unsigned sn;
        float2 eav;
        if constexpr (HASEA) {
            const uint2 ce = csr_e[k];
            sn = ce.x; eav = unpack_ea(ce.y);
        } else {
            sn = csr_psrc[k - koff];
        }
        float qr[COUT];
        load_hrow<COUT>(Q, (size_t)sn, qr);
        #pragma unroll
        for (int j = 0; j < COUT; ++j) {
            float m = pp[j] + qr[j];
            if constexpr (HASEA) m = fmaf(eav.x, we0[j], fmaf(eav.y, we1[j], m));
            acc[j] += fmaxf(fmaf(sc[j], m, bb[j]), 0.f);
        }
    }
    #pragma unroll
    for (int j = 0; j < COUT; ++j) {
        acc[j] += __shfl_xor(acc[j], 1, 64);
        acc[j] += __shfl_xor(acc[j], 2, 64);
    }
    if (quad == 0) {
        #pragma unroll
        for (int j = 0; j < COUT; ++j) agg_out[(size_t)i * COUT + j] = acc[j];
        if constexpr (FUSEQ) {
            float qrow[COUT2 > 0 ? COUT2 : 1];
            #pragma unroll
            for (int j2 = 0; j2 < COUT2; ++j2) {
                float q = h[0] * swn2[j2];
                #pragma unroll
                for (int k = 0; k < COUT; ++k)
                    q = fmaf(acc[k], swn2[(k + 1) * COUT2 + j2], q);
                qrow[j2] = q;
            }
            store_hrow<COUT2>(Qout, (size_t)i, qrow);
        }
    }
}

// ============================ fallback (R1, atomic scatter) ============================

__global__ __launch_bounds__(BLK) void zero_stats_kernel(double* __restrict__ stats, int n)
{
    int i = blockIdx.x * blockDim.x + threadIdx.x;
    if (i < n) stats[i] = 0.0;
}

template<int CIN, int COUT>
__global__ __launch_bounds__(BLK) void projPQ_kernel(
    const float* __restrict__ x, const float* __restrict__ agg_in,
    const float* __restrict__ ws, const float* __restrict__ wn,
    float* __restrict__ P, float* __restrict__ Q, float* __restrict__ agg_out, int n)
{
    __shared__ float sws[CIN * COUT], swn[CIN * COUT];
    for (int i = threadIdx.x; i < CIN * COUT; i += blockDim.x) { sws[i] = ws[i]; swn[i] = wn[i]; }
    __syncthreads();
    const int i = blockIdx.x * blockDim.x + threadIdx.x;
    if (i >= n) return;
    float h[CIN];
    h[0] = x[i];
    #pragma unroll
    for (int k = 1; k < CIN; ++k) h[k] = agg_in[(size_t)i * (CIN - 1) + (k - 1)];
    #pragma unroll
    for (int j = 0; j < COUT; ++j) {
        float p = 0.f, q = 0.f;
        #pragma unroll
        for (int k = 0; k < CIN; ++k) {
            p = fmaf(h[k], sws[k * COUT + j], p);
            q = fmaf(h[k], swn[k * COUT + j], q);
        }
        P[(size_t)i * COUT + j] = p;
        Q[(size_t)i * COUT + j] = q;
        agg_out[(size_t)i * COUT + j] = 0.f;
    }
}

template<int COUT, bool HASEA>
__global__ __launch_bounds__(BLK) void edge_stats_kernel(
    const int* __restrict__ esrc, const int* __restrict__ edst,
    const float* __restrict__ P,  const float* __restrict__ Q,
    const float* __restrict__ ea, const float* __restrict__ we,
    double* __restrict__ stats, int E)
{
    float we0[COUT], we1[COUT];
    if constexpr (HASEA) {
        #pragma unroll
        for (int j = 0; j < COUT; ++j) { we0[j] = we[j]; we1[j] = we[COUT + j]; }
    }
    float s[COUT], ss[COUT];
    #pragma unroll
    for (int j = 0; j < COUT; ++j) { s[j] = 0.f; ss[j] = 0.f; }
    const int stride = gridDim.x * blockDim.x;
    for (int e = blockIdx.x * blockDim.x + threadIdx.x; e < E; e += stride) {
        const int d = edst[e], sn = esrc[e];
        float2 eav = make_float2(0.f, 0.f);
        if constexpr (HASEA) eav = ((const float2* __restrict__)ea)[e];
        #pragma unroll
        for (int j = 0; j < COUT; ++j) {
            float m = P[(size_t)d * COUT + j] + Q[(size_t)sn * COUT + j];
            if constexpr (HASEA) m += eav.x * we0[j] + eav.y * we1[j];
            s[j] += m; ss[j] = fmaf(m, m, ss[j]);
        }
    }
    block_stats_reduce<COUT>(s, ss, stats);
}

template<int COUT, bool HASEA>
__global__ __launch_bounds__(BLK) void edge_scatter_kernel(
    const int* __restrict__ esrc, const int* __restrict__ edst,
    const float* __restrict__ P,  const float* __restrict__ Q,
    const float* __restrict__ ea, const float* __restrict__ we,
    const float* __restrict__ g,  const float* __restrict__ b,
    const double* __restrict__ stats,
    float* __restrict__ agg_out, int E)
{
    float we0[COUT], we1[COUT], sc[COUT], bb[COUT];
    #pragma unroll
    for (int j = 0; j < COUT; ++j) {
        if constexpr (HASEA) { we0[j] = we[j]; we1[j] = we[COUT + j]; }
    }
    bn_coefs<COUT>(stats, g, b, 1.0 / (double)E, sc, bb);
    const int stride = gridDim.x * blockDim.x;
    for (int e = blockIdx.x * blockDim.x + threadIdx.x; e < E; e += stride) {
        const int d = edst[e], sn = esrc[e];
        float2 eav = make_float2(0.f, 0.f);
        if constexpr (HASEA) eav = ((const float2* __restrict__)ea)[e];
        #pragma unroll
        for (int j = 0; j < COUT; ++j) {
            float m = P[(size_t)d * COUT + j] + Q[(size_t)sn * COUT + j];
            if constexpr (HASEA) m += eav.x * we0[j] + eav.y * we1[j];
            const float y = fmaxf(fmaf(sc[j], m, bb[j]), 0.f);
            if (y > 0.f) unsafeAtomicAdd(&agg_out[(size_t)d * COUT + j], y);
        }
    }
}

// ============================ node MLP + edge head (shared) ============================

__global__ __launch_bounds__(BLK) void mlp1_kernel(
    const float* __restrict__ x, const float* __restrict__ agg6,
    const float* __restrict__ pw1, const float* __restrict__ pb1,
    float* __restrict__ t1, double* __restrict__ stats, int n)
{
    __shared__ float w[13 * 8];
    __shared__ float bsh[8];
    for (int i = threadIdx.x; i < 13 * 8; i += blockDim.x) w[i] = pw1[i];
    if (threadIdx.x < 8) bsh[threadIdx.x] = pb1[threadIdx.x];
    __syncthreads();
    const int i = blockIdx.x * blockDim.x + threadIdx.x;
    float s[8], ss[8];
    #pragma unroll
    for (int j = 0; j < 8; ++j) { s[j] = 0.f; ss[j] = 0.f; }
    if (i < n) {
        float h[13];
        h[0] = x[i];
        #pragma unroll
        for (int k = 0; k < 12; ++k) h[k + 1] = agg6[(size_t)i * 12 + k];
        #pragma unroll
        for (int j = 0; j < 8; ++j) {
            float t = bsh[j];
            #pragma unroll
            for (int k = 0; k < 13; ++k) t = fmaf(h[k], w[k * 8 + j], t);
            t = fmaxf(t, 0.f);
            t1[(size_t)i * 8 + j] = t;
            s[j] = t; ss[j] = t * t;
        }
    }
    block_stats_reduce<8>(s, ss, stats);
}

__global__ __launch_bounds__(BLK) void mlp2_kernel(
    const float* __restrict__ t1,
    const float* __restrict__ p1g, const float* __restrict__ p1b,
    const float* __restrict__ pw2, const float* __restrict__ pb2,
    const double* __restrict__ stats1,
    float* __restrict__ t2, double* __restrict__ stats2, int n)
{
    float sc[8], bb[8];
    bn_coefs<8>(stats1, p1g, p1b, 1.0 / (double)n, sc, bb);
    const int i = blockIdx.x * blockDim.x + threadIdx.x;
    float s[4], ss[4];
    #pragma unroll
    for (int j = 0; j < 4; ++j) { s[j] = 0.f; ss[j] = 0.f; }
    if (i < n) {
        float u[8];
        #pragma unroll
        for (int j = 0; j < 8; ++j) u[j] = fmaf(sc[j], t1[(size_t)i * 8 + j], bb[j]);
        #pragma unroll
        for (int j2 = 0; j2 < 4; ++j2) {
            float t = pb2[j2];
            #pragma unroll
            for (int j = 0; j < 8; ++j) t = fmaf(u[j], pw2[j * 4 + j2], t);
            t = fmaxf(t, 0.f);
            t2[(size_t)i * 4 + j2] = t;
            s[j2] = t; ss[j2] = t * t;
        }
    }
    block_stats_reduce<4>(s, ss, stats2);
}

// mlp3 writes A/B as fp16 rows (stride 16 halves)
__global__ __launch_bounds__(BLK) void mlp3_kernel(
    const float* __restrict__ t2,
    const float* __restrict__ p2g, const float* __restrict__ p2b,
    const float* __restrict__ pw3, const float* __restrict__ pb3,
    const float* __restrict__ x, const float* __restrict__ agg6,
    const float* __restrict__ ew1, const float* __restrict__ eb1,
    const double* __restrict__ stats2,
    float* __restrict__ power_out, __half* __restrict__ A, __half* __restrict__ B, int n)
{
    __shared__ float w1[28 * 14];
    for (int i = threadIdx.x; i < 28 * 14; i += blockDim.x) w1[i] = ew1[i];
    __syncthreads();
    float sc[4], bb[4];
    bn_coefs<4>(stats2, p2g, p2b, 1.0 / (double)n, sc, bb);
    const int i = blockIdx.x * blockDim.x + threadIdx.x;
    if (i >= n) return;
    float z = pb3[0];
    #pragma unroll
    for (int j = 0; j < 4; ++j) z = fmaf(fmaf(sc[j], t2[(size_t)i * 4 + j], bb[j]), pw3[j], z);
    const float pw = sigmoid15(z);
    power_out[i] = pw;
    float h[14];
    h[0] = x[i];
    #pragma unroll
    for (int k = 0; k < 12; ++k) h[k + 1] = agg6[(size_t)i * 12 + k];
    h[13] = pw;
    float arow[14], brow[14];
    #pragma unroll
    for (int c = 0; c < 14; ++c) {
        float a = eb1[c], b2 = 0.f;
        #pragma unroll
        for (int k = 0; k < 14; ++k) {
            a  = fmaf(h[k], w1[k * 14 + c], a);
            b2 = fmaf(h[k], w1[(14 + k) * 14 + c], b2);
        }
        arow[c] = a; brow[c] = b2;
    }
    store_hrow<14>(A, (size_t)i, arow);
    store_hrow<14>(B, (size_t)i, brow);
}

__global__ __launch_bounds__(BLK) void ehead_stats_kernel(
    const int* __restrict__ dsrc, const int* __restrict__ ddst,
    const __half* __restrict__ A, const __half* __restrict__ B,
    double* __restrict__ stats, int E)
{
    float s[14], ss[14];
    #pragma unroll
    for (int j = 0; j < 14; ++j) { s[j] = 0.f; ss[j] = 0.f; }
    const int stride = gridDim.x * blockDim.x;
    for (int e = blockIdx.x * blockDim.x + threadIdx.x; e < E; e += stride) {
        const int dd = __builtin_nontemporal_load(&ddst[e]);
        const int ds = __builtin_nontemporal_load(&dsrc[e]);
        float ar[14], br[14];
        load_hrow<14>(A, (size_t)dd, ar);
        load_hrow<14>(B, (size_t)ds, br);
        #pragma unroll
        for (int c = 0; c < 14; ++c) {
            const float r = fmaxf(ar[c] + br[c], 0.f);
            s[c] += r; ss[c] = fmaf(r, r, ss[c]);
        }
    }
    block_stats_reduce<14>(s, ss, stats);
}

__global__ __launch_bounds__(BLK) void ehead_final_kernel(
    const int* __restrict__ dsrc, const int* __restrict__ ddst,
    const __half* __restrict__ A, const __half* __restrict__ B,
    const float* __restrict__ e1g, const float* __restrict__ e1b,
    const float* __restrict__ ew2, const float* __restrict__ eb2,
    const double* __restrict__ stats, float* __restrict__ dir_out, int E)
{
    float sc[14];
    float off = eb2[0];
    const double invE = 1.0 / (double)E;
    #pragma unroll
    for (int c = 0; c < 14; ++c) {
        const double mu  = stats[c] * invE;
        const double var = stats[16 + c] * invE - mu * mu;
        const float inv = rsqrtf((float)(var + (double)BN_EPS));
        const float gi = e1g[c] * inv;
        sc[c] = gi * ew2[c];
        off += (e1b[c] - (float)mu * gi) * ew2[c];
    }
    const int stride = gridDim.x * blockDim.x;
    for (int e = blockIdx.x * blockDim.x + threadIdx.x; e < E; e += stride) {
        const int dd = __builtin_nontemporal_load(&ddst[e]);
        const int ds = __builtin_nontemporal_load(&dsrc[e]);
        float ar[14], br[14];
        load_hrow<14>(A, (size_t)dd, ar);
        load_hrow<14>(B, (size_t)ds, br);
        float z = off;
        #pragma unroll
        for (int c = 0; c < 14; ++c) {
            const float r = fmaxf(ar[c] + br[c], 0.f);
            z = fmaf(r, sc[c], z);
        }
        dir_out[e] = sigmoid15(z);
    }
}

// ============================ launch ============================

extern "C" void kernel_launch(void* const* d_in, const int* in_sizes, int n_in,
                              void* d_out, int out_size, void* d_ws, size_t ws_size,
                              hipStream_t stream)
{
    const float* x    = (const float*)d_in[0];
    const float* ea   = (const float*)d_in[1];
    const int*   eidx = (const int*)d_in[2];
    const int*   didx = (const int*)d_in[3];
    const int*   pidx = (const int*)d_in[4];
    const float *c1_ws=(const float*)d_in[5],  *c1_wn=(const float*)d_in[6],  *c1_we=(const float*)d_in[7],  *c1_g=(const float*)d_in[8],  *c1_b=(const float*)d_in[9];
    const float *d1_ws=(const float*)d_in[10], *d1_wn=(const float*)d_in[11], *d1_g=(const float*)d_in[12], *d1_b=(const float*)d_in[13];
    const float *c2_ws=(const float*)d_in[14], *c2_wn=(const float*)d_in[15], *c2_we=(const float*)d_in[16], *c2_g=(const float*)d_in[17], *c2_b=(const float*)d_in[18];
    const float *d2_ws=(const float*)d_in[19], *d2_wn=(const float*)d_in[20], *d2_g=(const float*)d_in[21], *d2_b=(const float*)d_in[22];
    const float *c3_ws=(const float*)d_in[23], *c3_wn=(const float*)d_in[24], *c3_we=(const float*)d_in[25], *c3_g=(const float*)d_in[26], *c3_b=(const float*)d_in[27];
    const float *d3_ws=(const float*)d_in[28], *d3_wn=(const float*)d_in[29], *d3_g=(const float*)d_in[30], *d3_b=(const float*)d_in[31];
    const float *pw1=(const float*)d_in[32], *pb1=(const float*)d_in[33], *p1_g=(const float*)d_in[34], *p1_b=(const float*)d_in[35];
    const float *pw2=(const float*)d_in[36], *pb2=(const float*)d_in[37], *p2_g=(const float*)d_in[38], *p2_b=(const float*)d_in[39];
    const float *pw3=(const float*)d_in[40], *pb3=(const float*)d_in[41];
    const float *ew1=(const float*)d_in[42], *eb1=(const float*)d_in[43], *e1_g=(const float*)d_in[44], *e1_b=(const float*)d_in[45];
    const float *ew2=(const float*)d_in[46], *eb2=(const float*)d_in[47];

    const int N = in_sizes[0];
    const int E = in_sizes[2] / 2;
    const int n2 = 2 * N;
    const int *esrc = eidx,     *edst = eidx + E;
    const int *dsrc = didx,     *ddst = didx + E;
    const int *psrc = pidx,     *pdst = pidx + E;

    float* power_out = (float*)d_out;
    float* dir_out   = power_out + N;

    const int gN  = (N + BLK - 1) / BLK;
    const int g2  = (n2 + BLK - 1) / BLK;
    const int g4  = ((size_t)4 * N + BLK - 1) / BLK;   // 4 threads/node
    const int gE  = 1024;
    const int gEf = (E + BLK - 1) / BLK;
    const int gX  = 8 * 160;                           // 8 XCD groups x 160 blocks
    const float invE = 1.0f / (float)E;

    // ---- CSR-path workspace need (~36.9 MB) ----
    const size_t abBytes = (size_t)2 * N * 16 * sizeof(__half);  // A+B fp16 tables
    const size_t csreBytes0 = (size_t)8 * E;
    const size_t csreBytes = (csreBytes0 > abBytes) ? csreBytes0 : abBytes;
    const size_t need_csr = 4096
        + sizeof(__half) * (size_t)N * 16 * 2        /* Qa, Qb (max pad 16 halves) */
        + sizeof(float) * ((size_t)N * 12            /* aggA */
                         + (size_t)N * 12)           /* aggB */
        + csreBytes                                  /* csr_e / A,B */
        + sizeof(unsigned int) * (size_t)E           /* csr_psrc */
        + sizeof(int) * ((size_t)n2 + 2)             /* rowstart */
        + sizeof(int) * (size_t)n2                   /* cursor(=deg) */
        + sizeof(int) * 1024;                        /* partials */

    double* stats = (double*)d_ws;                   // 288 doubles

    if (ws_size >= need_csr) {
        // ================= CSR gather path =================
        char* p = (char*)d_ws + 4096;
        __half* Qa = (__half*)p;          p += sizeof(__half) * (size_t)N * 16;
        __half* Qb = (__half*)p;          p += sizeof(__half) * (size_t)N * 16;
        float* aggA = (float*)p;          p += sizeof(float) * (size_t)N * 12;
        float* aggB = (float*)p;          p += sizeof(float) * (size_t)N * 12;
        uint2* csr_e = (uint2*)p;         p += csreBytes;
        unsigned int* csr_psrc = (unsigned int*)p;  p += sizeof(unsigned int) * (size_t)E;
        int* rowstart = (int*)p;          p += sizeof(int) * ((size_t)n2 + 2);
        int* cursor   = (int*)p;                      // aliases deg
        int* deg      = cursor;
        int* partials = cursor + n2;
        float* t1   = aggA;                           // aggA free after conv stack
        float* t2   = aggA + (size_t)N * 8;
        __half* Abuf = (__half*)csr_e;                // csr_e dead after conv stack
        __half* Bbuf = Abuf + (size_t)N * 16;

        const int nparts = (n2 + 1023) / 1024;

        init_kernel<<<g2, BLK, 0, stream>>>(deg, stats, rowstart, n2, 2 * E);
        hist_kernel<<<gX, BLK, 0, stream>>>(edst, pdst, deg, N, E);
        scan1_kernel<<<nparts, 256, 0, stream>>>(deg, rowstart, partials, n2);
        scan2_kernel<<<1, 256, 0, stream>>>(partials, nparts);
        scan3_kernel<<<g2, BLK, 0, stream>>>(rowstart, cursor, partials, n2);
        fill_kernel<<<gX, BLK, 0, stream>>>(esrc, edst, psrc, pdst, ea, cursor, csr_e, csr_psrc, N, E);

        // L0: c1 (1->2, EA); agg fused with projQ for L1 (3,4)
        projQ_kernel<1, 2><<<gN, BLK, 0, stream>>>(x, nullptr, c1_wn, Qa, N);
        node_stats_kernel<1, 2, true><<<g4, BLK, 0, stream>>>(rowstart, csr_e, csr_psrc, x, nullptr, c1_ws, Qa, c1_we, stats + 0, N, 0, 0);
        node_agg_kernel<1, 2, true, 3, 4><<<g4, BLK, 0, stream>>>(rowstart, csr_e, csr_psrc, x, nullptr, c1_ws, Qa, c1_we, c1_g, c1_b, stats + 0, aggA, d1_wn, Qb, N, 0, 0, invE);
        // L1: d1 (3->4, prop); fused projQ for L2 (5,6)
        node_stats_kernel<3, 4, false><<<g4, BLK, 0, stream>>>(rowstart, csr_e, csr_psrc, x, aggA, d1_ws, Qb, nullptr, stats + 32, N, N, E);
        node_agg_kernel<3, 4, false, 5, 6><<<g4, BLK, 0, stream>>>(rowstart, csr_e, csr_psrc, x, aggA, d1_ws, Qb, nullptr, d1_g, d1_b, stats + 32, aggB, c2_wn, Qa, N, N, E, invE);
        // L2: c2 (5->6, EA); fused projQ for L3 (7,8)
        node_stats_kernel<5, 6, true><<<g4, BLK, 0, stream>>>(rowstart, csr_e, csr_psrc, x, aggB, c2_ws, Qa, c2_we, stats + 64, N, 0, 0);
        node_agg_kernel<5, 6, true, 7, 8><<<g4, BLK, 0, stream>>>(rowstart, csr_e, csr_psrc, x, aggB, c2_ws, Qa, c2_we, c2_g, c2_b, stats + 64, aggA, d2_wn, Qb, N, 0, 0, invE);
        // L3: d2 (7->8, prop); fused projQ for L4 (9,10)
        node_stats_kernel<7, 8, false><<<g4, BLK, 0, stream>>>(rowstart, csr_e, csr_psrc, x, aggA, d2_ws, Qb, nullptr, stats + 96, N, N, E);
        node_agg_kernel<7, 8, false, 9, 10><<<g4, BLK, 0, stream>>>(rowstart, csr_e, csr_psrc, x, aggA, d2_ws, Qb, nullptr, d2_g, d2_b, stats + 96, aggB, c3_wn, Qa, N, N, E, invE);
        // L4: c3 (9->10, EA); fused projQ for L5 (11,12)
        node_stats_kernel<9, 10, true><<<g4, BLK, 0, stream>>>(rowstart, csr_e, csr_psrc, x, aggB, c3_ws, Qa, c3_we, stats + 128, N, 0, 0);
        node_agg_kernel<9, 10, true, 11, 12><<<g4, BLK, 0, stream>>>(rowstart, csr_e, csr_psrc, x, aggB, c3_ws, Qa, c3_we, c3_g, c3_b, stats + 128, aggA, d3_wn, Qb, N, 0, 0, invE);
        // L5: d3 (11->12, prop); no fuse
        node_stats_kernel<11, 12, false><<<g4, BLK, 0, stream>>>(rowstart, csr_e, csr_psrc, x, aggA, d3_ws, Qb, nullptr, stats + 160, N, N, E);
        node_agg_kernel<11, 12, false, 0, 0><<<g4, BLK, 0, stream>>>(rowstart, csr_e, csr_psrc, x, aggA, d3_ws, Qb, nullptr, d3_g, d3_b, stats + 160, aggB, nullptr, nullptr, N, N, E, invE);

        mlp1_kernel<<<gN, BLK, 0, stream>>>(x, aggB, pw1, pb1, t1, stats + 192, N);
        mlp2_kernel<<<gN, BLK, 0, stream>>>(t1, p1_g, p1_b, pw2, pb2, stats + 192, t2, stats + 224, N);
        mlp3_kernel<<<gN, BLK, 0, stream>>>(t2, p2_g, p2_b, pw3, pb3, x, aggB, ew1, eb1, stats + 224,
                                            power_out, Abuf, Bbuf, N);
        ehead_stats_kernel<<<gE, BLK, 0, stream>>>(dsrc, ddst, Abuf, Bbuf, stats + 256, E);
        ehead_final_kernel<<<gEf, BLK, 0, stream>>>(dsrc, ddst, Abuf, Bbuf, e1_g, e1_b, ew2, eb2,
                                                    stats + 256, dir_out, E);
    } else {
        // ================= fallback: R1 atomic-scatter path (proven) =================
        float* fws  = (float*)((char*)d_ws + 4096);
        float* P    = fws;                fws += (size_t)N * 14;
        float* Q    = fws;                fws += (size_t)N * 14;
        float* aggA = fws;                fws += (size_t)N * 12;
        float* aggB = fws;                fws += (size_t)N * 12;
        float* t1   = aggA;
        float* t2   = aggA + (size_t)N * 8;
        __half* Abuf = (__half*)P;        // fp16 rows stride 16 (3.2 MB each, fits in P/Q)
        __half* Bbuf = (__half*)Q;

        zero_stats_kernel<<<2, BLK, 0, stream>>>(stats, 288);

        projPQ_kernel<1, 2><<<gN, BLK, 0, stream>>>(x, nullptr, c1_ws, c1_wn, P, Q, aggA, N);
        edge_stats_kernel<2, true><<<gE, BLK, 0, stream>>>(esrc, edst, P, Q, ea, c1_we, stats + 0, E);
        edge_scatter_kernel<2, true><<<gE, BLK, 0, stream>>>(esrc, edst, P, Q, ea, c1_we, c1_g, c1_b, stats + 0, aggA, E);

        projPQ_kernel<3, 4><<<gN, BLK, 0, stream>>>(x, aggA, d1_ws, d1_wn, P, Q, aggB, N);
        edge_stats_kernel<4, false><<<gE, BLK, 0, stream>>>(psrc, pdst, P, Q, nullptr, nullptr, stats + 32, E);
        edge_scatter_kernel<4, false><<<gE, BLK, 0, stream>>>(psrc, pdst, P, Q, nullptr, nullptr, d1_g, d1_b, stats + 32, aggB, E);

        projPQ_kernel<5, 6><<<gN, BLK, 0, stream>>>(x, aggB, c2_ws, c2_wn, P, Q, aggA, N);
        edge_stats_kernel<6, true><<<gE, BLK, 0, stream>>>(esrc, edst, P, Q, ea, c2_we, stats + 64, E);
        edge_scatter_kernel<6, true><<<gE, BLK, 0, stream>>>(esrc, edst, P, Q, ea, c2_we, c2_g, c2_b, stats + 64, aggA, E);

        projPQ_kernel<7, 8><<<gN, BLK, 0, stream>>>(x, aggA, d2_ws, d2_wn, P, Q, aggB, N);
        edge_stats_kernel<8, false><<<gE, BLK, 0, stream>>>(psrc, pdst, P, Q, nullptr, nullptr, stats + 96, E);
        edge_scatter_kernel<8, false><<<gE, BLK, 0, stream>>>(psrc, pdst, P, Q, nullptr, nullptr, d2_g, d2_b, stats + 96, aggB, E);

        projPQ_kernel<9, 10><<<gN, BLK, 0, stream>>>(x, aggB, c3_ws, c3_wn, P, Q, aggA, N);
        edge_stats_kernel<10, true><<<gE, BLK, 0, stream>>>(esrc, edst, P, Q, ea, c3_we, stats + 128, E);
        edge_scatter_kernel<10, true><<<gE, BLK, 0, stream>>>(esrc, edst, P, Q, ea, c3_we, c3_g, c3_b, stats + 128, aggA, E);

        projPQ_kernel<11, 12><<<gN, BLK, 0, stream>>>(x, aggA, d3_ws, d3_wn, P, Q, aggB, N);
        edge_stats_kernel<12, false><<<gE, BLK, 0, stream>>>(psrc, pdst, P, Q, nullptr, nullptr, stats + 160, E);
        edge_scatter_kernel<12, false><<<gE, BLK, 0, stream>>>(psrc, pdst, P, Q, nullptr, nullptr, d3_g, d3_b, stats + 160, aggB, E);

        mlp1_kernel<<<gN, BLK, 0, stream>>>(x, aggB, pw1, pb1, t1, stats + 192, N);
        mlp2_kernel<<<gN, BLK, 0, stream>>>(t1, p1_g, p1_b, pw2, pb2, stats + 192, t2, stats + 224, N);
        mlp3_kernel<<<gN, BLK, 0, stream>>>(t2, p2_g, p2_b, pw3, pb3, x, aggB, ew1, eb1, stats + 224,
                                            power_out, Abuf, Bbuf, N);
        ehead_stats_kernel<<<gE, BLK, 0, stream>>>(dsrc, ddst, Abuf, Bbuf, stats + 256, E);
        ehead_final_kernel<<<gE, BLK, 0, stream>>>(dsrc, ddst, Abuf, Bbuf, e1_g, e1_b, ew2, eb2,
                                                   stats + 256, dir_out, E);
    }
}